// Round 3
// baseline (4472.237 us; speedup 1.0000x reference)
//
#include <hip/hip_runtime.h>
#include <hip/hip_bf16.h>

// SGNO1d: B=16, X=16384, Xp=16386, W=64, H=128, M=64, NB=4.
// Inputs fp32, output fp32 (reference output dtype; comparison is bf16-lenient).
// out_hat has only 64 nonzero modes -> rfft/irfft become dense DFT matmuls
// with a precomputed (Xp x 64 x {cos,sin}) fp32 basis.

#define BB 16
#define X 16384
#define XP 16386
#define W 64
#define H 128
#define M 64
#define NB 4
#define NIN 31
#define NC 3

typedef __hip_bfloat16 bf16;

__device__ __forceinline__ float b2f(bf16 v){ return __bfloat162float(v); }
__device__ __forceinline__ float gelu_f(float t){
  return 0.5f * t * (1.0f + erff(t * 0.70710678118654752440f));
}
__device__ __forceinline__ float softplus_f(float v){
  return (v > 20.f) ? v : log1pf(expf(v));
}

// ---------------- precompute ----------------
__global__ __launch_bounds__(256) void k_basis(float* __restrict__ basis){
  int idx = blockIdx.x * 256 + threadIdx.x;
  if (idx >= XP * M) return;
  int x = idx >> 6, m = idx & 63;
  int tt = (int)(((long long)x * (long long)m) % XP);
  float ang = 6.283185307179586477f * (float)tt / (float)XP;
  float s, c;
  sincosf(ang, &s, &c);
  basis[(size_t)x * 128 + 2 * m]     = c;
  basis[(size_t)x * 128 + 2 * m + 1] = s;
}

__global__ __launch_bounds__(256) void k_decay(const float* __restrict__ log_decay,
                                               float* __restrict__ expz,
                                               float* __restrict__ phi){
  int idx = blockIdx.x * 256 + threadIdx.x;
  if (idx >= NB * W * M) return;
  float v = log_decay[idx];
  float z = -softplus_f(v);
  expz[idx] = expf(z);
  float p;
  if (fabsf(z) < 1e-6f) p = 1.0f + 0.5f * z + z * z * (1.0f / 6.0f);
  else                  p = expm1f(z) / z;
  phi[idx] = p;
}

__global__ void k_filt(float* __restrict__ filt){
  int m = threadIdx.x;
  if (m < M){
    float g = (float)m / 63.0f;
    float r2 = g * g + 1e-12f;
    float r4 = r2 * r2;
    float r8 = r4 * r4;
    filt[m] = expf(-2.0f * r8);
  }
}

// ---------------- fc0: (x,grid) -> h[b][c][xp], pad cols zeroed ----------------
__global__ __launch_bounds__(256) void k_fc0(const float* __restrict__ xg,
                                             const float* __restrict__ gg,
                                             const float* __restrict__ wg,
                                             const float* __restrict__ bg,
                                             float* __restrict__ h){
  __shared__ float xs[256][33];
  __shared__ float wsh[W][NIN];
  int b = blockIdx.y, x0 = blockIdx.x * 256, t = threadIdx.x;
  for (int i = t; i < W * NIN; i += 256) wsh[i / NIN][i % NIN] = wg[i];
  for (int i = t; i < 256 * 30; i += 256){
    int p = i / 30, f = i - p * 30, gx = x0 + p;
    xs[p][f] = (gx < X) ? xg[((size_t)b * X + gx) * 30 + f] : 0.f;
  }
  { int gx = x0 + t; xs[t][30] = (gx < X) ? gg[(size_t)b * X + gx] : 0.f; }
  __syncthreads();
  int gx = x0 + t;
  if (gx >= XP) return;
  if (gx >= X){
    for (int c = 0; c < W; ++c) h[((size_t)b * W + c) * XP + gx] = 0.f;
    return;
  }
  for (int c = 0; c < W; ++c){
    float a = bg[c];
    #pragma unroll
    for (int f = 0; f < NIN; ++f) a = fmaf(wsh[c][f], xs[t][f], a);
    h[((size_t)b * W + c) * XP + gx] = a;
  }
}

// ---------------- gMLP: g = ag*(W2 @ gelu(W1 @ h + b1) + b2) ----------------
// LDS: hT 16K + wb16 16.6K + gms 16K = 49.4KB (< 64KB)
__global__ __launch_bounds__(256) void k_gmlp(const float* __restrict__ h,
                                              const float* __restrict__ w1g,
                                              const float* __restrict__ b1g,
                                              const float* __restrict__ w2g,
                                              const float* __restrict__ b2g,
                                              const float* __restrict__ agr,
                                              float* __restrict__ g, int blk){
  __shared__ float hT[64][64];
  __shared__ bf16  wb16[128 * 65];
  __shared__ bf16  gms[128][64];
  int b = blockIdx.y, x0 = blockIdx.x * 64, t = threadIdx.x;
  float ag = softplus_f(agr[0]);
  const float* w1 = w1g + blk * H * W;
  const float* w2 = w2g + blk * W * H;
  for (int i = t; i < 64 * 64; i += 256){
    int c = i >> 6, xl = i & 63, gx = x0 + xl;
    hT[c][xl] = (gx < XP) ? h[((size_t)b * W + c) * XP + gx] : 0.f;
  }
  for (int i = t; i < H * W; i += 256)
    wb16[(i >> 6) * 65 + (i & 63)] = __float2bfloat16(w1[i]);
  __syncthreads();
  int xq = t & 15, oq = t >> 4;
  {
    float acc[8][4];
    #pragma unroll
    for (int j = 0; j < 8; ++j)
      #pragma unroll
      for (int k = 0; k < 4; ++k) acc[j][k] = 0.f;
    for (int c = 0; c < W; ++c){
      float hv[4];
      #pragma unroll
      for (int k = 0; k < 4; ++k) hv[k] = hT[c][xq + 16 * k];
      #pragma unroll
      for (int j = 0; j < 8; ++j){
        float wv = b2f(wb16[(oq * 8 + j) * 65 + c]);
        #pragma unroll
        for (int k = 0; k < 4; ++k) acc[j][k] = fmaf(wv, hv[k], acc[j][k]);
      }
    }
    #pragma unroll
    for (int j = 0; j < 8; ++j){
      float bv = b1g[blk * H + oq * 8 + j];
      #pragma unroll
      for (int k = 0; k < 4; ++k)
        gms[oq * 8 + j][xq + 16 * k] = __float2bfloat16(gelu_f(acc[j][k] + bv));
    }
  }
  __syncthreads();
  for (int i = t; i < W * H; i += 256)
    wb16[(i >> 7) * 129 + (i & 127)] = __float2bfloat16(w2[i]);
  __syncthreads();
  {
    float acc[4][4];
    #pragma unroll
    for (int j = 0; j < 4; ++j)
      #pragma unroll
      for (int k = 0; k < 4; ++k) acc[j][k] = 0.f;
    for (int c = 0; c < H; ++c){
      float gv[4];
      #pragma unroll
      for (int k = 0; k < 4; ++k) gv[k] = b2f(gms[c][xq + 16 * k]);
      #pragma unroll
      for (int j = 0; j < 4; ++j){
        float wv = b2f(wb16[(oq * 4 + j) * 129 + c]);
        #pragma unroll
        for (int k = 0; k < 4; ++k) acc[j][k] = fmaf(wv, gv[k], acc[j][k]);
      }
    }
    #pragma unroll
    for (int j = 0; j < 4; ++j){
      int o = oq * 4 + j;
      float bv = b2g[blk * W + o];
      #pragma unroll
      for (int k = 0; k < 4; ++k){
        int gx = x0 + xq + 16 * k;
        if (gx < XP) g[((size_t)b * W + o) * XP + gx] = ag * (acc[j][k] + bv);
      }
    }
  }
}

// ---------------- DFT (first 64 modes), split-K with fp32 atomics ----------------
__global__ __launch_bounds__(256) void k_dft(const float* __restrict__ hsrc,
                                             const float* __restrict__ gsrc,
                                             const float* __restrict__ basis,
                                             float* __restrict__ vhat,
                                             float* __restrict__ ghat){
  __shared__ float hs[64][33];
  __shared__ float bs[32][128];
  const float* src = blockIdx.z ? gsrc : hsrc;
  float* dst       = blockIdx.z ? ghat : vhat;
  int b = blockIdx.y;
  int x0 = blockIdx.x * 512;
  int t = threadIdx.x;
  int mq = t & 15, cq = t >> 4;
  float acc[4][8];
  #pragma unroll
  for (int i = 0; i < 4; ++i)
    #pragma unroll
    for (int j = 0; j < 8; ++j) acc[i][j] = 0.f;
  int xend = x0 + 512; if (xend > XP) xend = XP;
  for (int xs0 = x0; xs0 < xend; xs0 += 32){
    __syncthreads();
    for (int i = t; i < 64 * 32; i += 256){
      int c = i >> 5, xl = i & 31, gx = xs0 + xl;
      hs[c][xl] = (gx < XP) ? src[((size_t)b * W + c) * XP + gx] : 0.f;
    }
    for (int i = t * 4; i < 32 * 128; i += 1024){
      int xl = i >> 7, mp = i & 127, gx = xs0 + xl;
      float4 v;
      if (gx < XP) v = *(const float4*)&basis[(size_t)gx * 128 + mp];
      else { v.x = v.y = v.z = v.w = 0.f; }
      *(float4*)&bs[xl][mp] = v;
    }
    __syncthreads();
    int nx = xend - xs0; if (nx > 32) nx = 32;
    for (int xl = 0; xl < nx; ++xl){
      float hv[4];
      #pragma unroll
      for (int i = 0; i < 4; ++i) hv[i] = hs[cq * 4 + i][xl];
      const float4* bp = (const float4*)&bs[xl][mq * 8];
      float4 b0 = bp[0], b1 = bp[1];
      float bv[8] = {b0.x, b0.y, b0.z, b0.w, b1.x, b1.y, b1.z, b1.w};
      #pragma unroll
      for (int i = 0; i < 4; ++i)
        #pragma unroll
        for (int j = 0; j < 8; ++j) acc[i][j] = fmaf(hv[i], bv[j], acc[i][j]);
    }
  }
  #pragma unroll
  for (int i = 0; i < 4; ++i)
    #pragma unroll
    for (int j = 0; j < 8; ++j){
      int c = cq * 4 + i, mp = mq * 8 + j;
      float v = (mp & 1) ? -acc[i][j] : acc[i][j];  // im = -sum(h*sin)
      atomicAdd(&dst[((size_t)b * W + c) * 128 + mp], v);
    }
}

// ---------------- out_m = scale*(expz*v_hat + phi*filt*(g_hat @ mix)) ----------------
__global__ void k_outm(const float* __restrict__ vhat, const float* __restrict__ ghat,
                       const float* __restrict__ mix_re, const float* __restrict__ mix_im,
                       const float* __restrict__ expz, const float* __restrict__ phi,
                       const float* __restrict__ filt, float* __restrict__ outm, int blk){
  int b = blockIdx.y, o = blockIdx.x, m = threadIdx.x;
  const float* mre = mix_re + (size_t)blk * W * W * M + (size_t)o * M + m;
  const float* mim = mix_im + (size_t)blk * W * W * M + (size_t)o * M + m;
  float gr = 0.f, gi = 0.f;
  for (int i = 0; i < W; ++i){
    float gre = ghat[((size_t)b * W + i) * 128 + 2 * m];
    float gim = ghat[((size_t)b * W + i) * 128 + 2 * m + 1];
    float xr = mre[(size_t)i * W * M];
    float xi = mim[(size_t)i * W * M];
    gr = fmaf(gre, xr, gr); gr = fmaf(-gim, xi, gr);
    gi = fmaf(gre, xi, gi); gi = fmaf( gim, xr, gi);
  }
  int om = blk * W * M + o * M + m;
  float ez = expz[om], ph = phi[om], fl = filt[m];
  float vr = vhat[((size_t)b * W + o) * 128 + 2 * m];
  float vi = vhat[((size_t)b * W + o) * 128 + 2 * m + 1];
  float outr = fmaf(ez, vr, ph * fl * gr);
  float outi = fmaf(ez, vi, ph * fl * gi);
  float sc = ((m == 0) ? 1.0f : 2.0f) / (float)XP;  // fold irfft scaling
  outm[((size_t)b * W + o) * 128 + 2 * m]     = outr * sc;
  outm[((size_t)b * W + o) * 128 + 2 * m + 1] = outi * sc;
}

// ---------------- update: h = act(iDFT(out_m) + aw*(Wh + b)) in place ----------------
// x-tile = 32: hT 8.4K + om 32K + bT 16.9K = 57.3KB LDS
__global__ __launch_bounds__(256) void k_update(float* __restrict__ h,
                                                const float* __restrict__ outm,
                                                const float* __restrict__ basis,
                                                const float* __restrict__ wwg,
                                                const float* __restrict__ wbg,
                                                const float* __restrict__ awr, int blk){
  __shared__ float hT[64][33];
  __shared__ float om[64][128];   // [m][2o + {re,im}]
  __shared__ float bT[64][66];    // [m][x(cos) | 33+x(sin)]
  int b = blockIdx.y, x0 = blockIdx.x * 32, t = threadIdx.x;
  float aw = softplus_f(awr[0]);
  const float* ww = wwg + blk * W * W;
  for (int i = t; i < 64 * 32; i += 256){
    int c = i >> 5, xl = i & 31, gx = x0 + xl;
    hT[c][xl] = (gx < XP) ? h[((size_t)b * W + c) * XP + gx] : 0.f;
  }
  for (int i = t; i < 8192; i += 256){
    int o = i >> 7, mp = i & 127;
    om[mp >> 1][o * 2 + (mp & 1)] = outm[(size_t)b * 8192 + i];
  }
  for (int i = t * 4; i < 32 * 128; i += 1024){
    int xl = i >> 7, mp = i & 127, gx = x0 + xl;
    float4 v;
    if (gx < XP) v = *(const float4*)&basis[(size_t)gx * 128 + mp];
    else { v.x = v.y = v.z = v.w = 0.f; }
    int m0 = mp >> 1;
    bT[m0][xl] = v.x;     bT[m0][33 + xl] = v.y;
    bT[m0 + 1][xl] = v.z; bT[m0 + 1][33 + xl] = v.w;
  }
  __syncthreads();
  int xq = t & 7, oq = t >> 3;       // 8 x-slots x 32 o-slots
  float accW[2][4], accE[2][4];
  #pragma unroll
  for (int j = 0; j < 2; ++j)
    #pragma unroll
    for (int k = 0; k < 4; ++k){ accW[j][k] = 0.f; accE[j][k] = 0.f; }
  for (int c = 0; c < W; ++c){
    float hv[4];
    #pragma unroll
    for (int k = 0; k < 4; ++k) hv[k] = hT[c][xq + 8 * k];
    #pragma unroll
    for (int j = 0; j < 2; ++j){
      float wv = ww[(oq * 2 + j) * W + c];
      #pragma unroll
      for (int k = 0; k < 4; ++k) accW[j][k] = fmaf(wv, hv[k], accW[j][k]);
    }
  }
  for (int m = 0; m < M; ++m){
    float cv[4], sv[4];
    #pragma unroll
    for (int k = 0; k < 4; ++k){
      cv[k] = bT[m][xq + 8 * k];
      sv[k] = bT[m][33 + xq + 8 * k];
    }
    #pragma unroll
    for (int j = 0; j < 2; ++j){
      float orv = om[m][(oq * 2 + j) * 2];
      float oiv = om[m][(oq * 2 + j) * 2 + 1];
      #pragma unroll
      for (int k = 0; k < 4; ++k){
        accE[j][k] = fmaf(orv, cv[k], accE[j][k]);
        accE[j][k] = fmaf(-oiv, sv[k], accE[j][k]);
      }
    }
  }
  #pragma unroll
  for (int j = 0; j < 2; ++j){
    int o = oq * 2 + j;
    float wbv = wbg[blk * W + o];
    #pragma unroll
    for (int k = 0; k < 4; ++k){
      int gx = x0 + xq + 8 * k;
      if (gx < XP){
        float u = accE[j][k] + aw * (accW[j][k] + wbv);
        if (blk != NB - 1) u = gelu_f(u);
        h[((size_t)b * W + o) * XP + gx] = u;
      }
    }
  }
}

// ---------------- fc1 + gelu + fc2 -> out (fp32) ----------------
__global__ __launch_bounds__(256) void k_fc12(const float* __restrict__ h,
                                              const float* __restrict__ w1,
                                              const float* __restrict__ b1,
                                              const float* __restrict__ w2,
                                              const float* __restrict__ b2,
                                              float* __restrict__ out){
  __shared__ float hT[64][64];
  __shared__ float w1s[128][65];
  __shared__ float red[4][64][NC];
  int b = blockIdx.y, x0 = blockIdx.x * 64, t = threadIdx.x;
  for (int i = t; i < 64 * 64; i += 256){
    int c = i >> 6, xl = i & 63;
    hT[c][xl] = h[((size_t)b * W + c) * XP + x0 + xl];
  }
  for (int i = t; i < 128 * 64; i += 256) w1s[i >> 6][i & 63] = w1[i];
  __syncthreads();
  int xl = t & 63, j = t >> 6;
  float acc[NC] = {0.f, 0.f, 0.f};
  for (int oi = 0; oi < 32; ++oi){
    int o = j * 32 + oi;
    float a = b1[o];
    #pragma unroll 16
    for (int c = 0; c < W; ++c) a = fmaf(w1s[o][c], hT[c][xl], a);
    a = gelu_f(a);
    #pragma unroll
    for (int n = 0; n < NC; ++n) acc[n] = fmaf(w2[n * 128 + o], a, acc[n]);
  }
  #pragma unroll
  for (int n = 0; n < NC; ++n) red[j][xl][n] = acc[n];
  __syncthreads();
  if (j == 0){
    #pragma unroll
    for (int n = 0; n < NC; ++n){
      float v = red[0][xl][n] + red[1][xl][n] + red[2][xl][n] + red[3][xl][n] + b2[n];
      out[((size_t)b * X + x0 + xl) * NC + n] = v;
    }
  }
}

extern "C" void kernel_launch(void* const* d_in, const int* in_sizes, int n_in,
                              void* d_out, int out_size, void* d_ws, size_t ws_size,
                              hipStream_t stream){
  (void)in_sizes; (void)n_in; (void)out_size; (void)ws_size;
  const float* x        = (const float*)d_in[0];
  const float* grid     = (const float*)d_in[1];
  const float* fc0_w    = (const float*)d_in[2];
  const float* fc0_b    = (const float*)d_in[3];
  const float* fc1_w    = (const float*)d_in[4];
  const float* fc1_b    = (const float*)d_in[5];
  const float* fc2_w    = (const float*)d_in[6];
  const float* fc2_b    = (const float*)d_in[7];
  const float* g_w1     = (const float*)d_in[8];
  const float* g_b1     = (const float*)d_in[9];
  const float* g_w2     = (const float*)d_in[10];
  const float* g_b2     = (const float*)d_in[11];
  const float* w_w      = (const float*)d_in[12];
  const float* w_b      = (const float*)d_in[13];
  const float* log_dec  = (const float*)d_in[14];
  const float* mix_re   = (const float*)d_in[15];
  const float* mix_im   = (const float*)d_in[16];
  const float* a_w      = (const float*)d_in[17];
  const float* a_g      = (const float*)d_in[18];
  float* out = (float*)d_out;

  float* wsf = (float*)d_ws;
  size_t off = 0;
  float* basis = wsf + off; off += (size_t)XP * 128;      // 2,097,408
  float* h     = wsf + off; off += (size_t)BB * W * XP;   // 16,779,264
  float* g     = wsf + off; off += (size_t)BB * W * XP;
  float* vhat  = wsf + off; off += (size_t)BB * W * 128;  // 131,072
  float* ghat  = wsf + off; off += (size_t)BB * W * 128;
  float* outm  = wsf + off; off += (size_t)BB * W * 128;
  float* expz  = wsf + off; off += (size_t)NB * W * M;
  float* phi   = wsf + off; off += (size_t)NB * W * M;
  float* filt  = wsf + off; off += 64;

  k_basis<<<dim3((XP * M + 255) / 256), 256, 0, stream>>>(basis);
  k_decay<<<dim3((NB * W * M + 255) / 256), 256, 0, stream>>>(log_dec, expz, phi);
  k_filt<<<1, 64, 0, stream>>>(filt);
  k_fc0<<<dim3((XP + 255) / 256, BB), 256, 0, stream>>>(x, grid, fc0_w, fc0_b, h);

  for (int blk = 0; blk < NB; ++blk){
    k_gmlp<<<dim3((XP + 63) / 64, BB), 256, 0, stream>>>(h, g_w1, g_b1, g_w2, g_b2, a_g, g, blk);
    hipMemsetAsync(vhat, 0, (size_t)2 * BB * W * 128 * sizeof(float), stream);
    k_dft<<<dim3((XP + 511) / 512, BB, 2), 256, 0, stream>>>(h, g, basis, vhat, ghat);
    k_outm<<<dim3(W, BB), 64, 0, stream>>>(vhat, ghat, mix_re, mix_im, expz, phi, filt, outm, blk);
    k_update<<<dim3((XP + 31) / 32, BB), 256, 0, stream>>>(h, outm, basis, w_w, w_b, a_w, blk);
  }
  k_fc12<<<dim3(X / 64, BB), 256, 0, stream>>>(h, fc1_w, fc1_b, fc2_w, fc2_b, out);
}

// Round 4
// 1741.778 us; speedup vs baseline: 2.5676x; 2.5676x over previous
//
#include <hip/hip_runtime.h>
#include <hip/hip_bf16.h>

// SGNO1d: B=16, X=16384, Xp=16386, W=64, H=128, M=64, NB=4.
// MFMA bf16 rewrite. Key identities:
//  - only 64 modes survive -> rfft/irfft are dense DFT GEMMs (K=16386 / K=128)
//  - DFT linearity: ghat = ag*(W2 @ DFT(gmid) + b2*XP*delta_m0)  -> g never materialized
// All accumulation fp32; bf16 only on MFMA operands.

#define BB 16
#define X 16384
#define XP 16386
#define XPAD 16512   // 129*128, zero-padded tail for tile-uniform MFMA
#define W 64
#define H 128
#define M 64
#define NB 4
#define NIN 31
#define NC 3

typedef __hip_bfloat16 bf16;
typedef __attribute__((ext_vector_type(8))) short short8;
typedef __attribute__((ext_vector_type(4))) float floatx4;

__device__ __forceinline__ float gelu_f(float t){
  return 0.5f * t * (1.0f + erff(t * 0.70710678118654752440f));
}
__device__ __forceinline__ float softplus_f(float v){
  return (v > 20.f) ? v : log1pf(expf(v));
}
__device__ __forceinline__ short f2bs(float f){   // fp32 -> bf16 bits (RNE)
  union { float f; unsigned u; } v; v.f = f;
  unsigned r = (v.u + 0x7FFFu + ((v.u >> 16) & 1u)) >> 16;
  return (short)r;
}
__device__ __forceinline__ float bs2f(short s){
  union { unsigned u; float f; } v; v.u = ((unsigned)(unsigned short)s) << 16;
  return v.f;
}
#define MFMA(a,b,c) __builtin_amdgcn_mfma_f32_16x16x32_bf16((a),(b),(c),0,0,0)

// ---------------- precompute: two bf16 DFT bases ----------------
// basT16[mp][x]  (mp=2m:cos, 2m+1:+sin), rows along x   -> DFT B-operand
// basC16[x][kp]  (kp=2m:cos, 2m+1:-sin), rows along kp  -> iDFT A-operand
__global__ __launch_bounds__(256) void k_basis(short* __restrict__ basT16,
                                               short* __restrict__ basC16){
  int idx = blockIdx.x * 256 + threadIdx.x;
  if (idx >= XPAD * M) return;
  int x = idx >> 6, m = idx & 63;
  short cb = 0, sb = 0, nsb = 0;
  if (x < XP){
    int tt = (int)(((long long)x * (long long)m) % XP);
    float ang = 6.283185307179586477f * (float)tt / (float)XP;
    float s, c; sincosf(ang, &s, &c);
    cb = f2bs(c); sb = f2bs(s); nsb = f2bs(-s);
  }
  basT16[(size_t)(2*m)   * XPAD + x] = cb;
  basT16[(size_t)(2*m+1) * XPAD + x] = sb;
  basC16[(size_t)x * 128 + 2*m]     = cb;
  basC16[(size_t)x * 128 + 2*m + 1] = nsb;
}

__global__ __launch_bounds__(256) void k_decay(const float* __restrict__ log_decay,
                                               float* __restrict__ expz,
                                               float* __restrict__ phi){
  int idx = blockIdx.x * 256 + threadIdx.x;
  if (idx >= NB * W * M) return;
  float z = -softplus_f(log_decay[idx]);
  expz[idx] = expf(z);
  float p;
  if (fabsf(z) < 1e-6f) p = 1.0f + 0.5f * z + z * z * (1.0f / 6.0f);
  else                  p = expm1f(z) / z;
  phi[idx] = p;
}

__global__ void k_filt(float* __restrict__ filt){
  int m = threadIdx.x;
  if (m < M){
    float g = (float)m / 63.0f;
    float r2 = g * g + 1e-12f;
    float r4 = r2 * r2;
    float r8 = r4 * r4;
    filt[m] = expf(-2.0f * r8);
  }
}

// bf16 weight copies: ww16 = aw*w_w, w116 = g_w1, w1fc16 = fc1_w (all rows along c=K)
__global__ __launch_bounds__(256) void k_prep(const float* __restrict__ w_w,
                                              const float* __restrict__ g_w1,
                                              const float* __restrict__ fc1_w,
                                              const float* __restrict__ awr,
                                              short* __restrict__ ww16,
                                              short* __restrict__ w116,
                                              short* __restrict__ w1fc16){
  int idx = blockIdx.x * 256 + threadIdx.x;
  float aw = softplus_f(awr[0]);
  if (idx < 16384){ ww16[idx] = f2bs(aw * w_w[idx]); }
  else if (idx < 49152){ int i = idx - 16384; w116[i] = f2bs(g_w1[i]); }
  else if (idx < 57344){ int i = idx - 49152; w1fc16[i] = f2bs(fc1_w[i]); }
}

// ---------------- fc0 (unchanged, VALU) ----------------
__global__ __launch_bounds__(256) void k_fc0(const float* __restrict__ xg,
                                             const float* __restrict__ gg,
                                             const float* __restrict__ wg,
                                             const float* __restrict__ bg,
                                             float* __restrict__ h){
  __shared__ float xs[256][33];
  __shared__ float wsh[W][NIN];
  int b = blockIdx.y, x0 = blockIdx.x * 256, t = threadIdx.x;
  for (int i = t; i < W * NIN; i += 256) wsh[i / NIN][i % NIN] = wg[i];
  for (int i = t; i < 256 * 30; i += 256){
    int p = i / 30, f = i - p * 30, gx = x0 + p;
    xs[p][f] = (gx < X) ? xg[((size_t)b * X + gx) * 30 + f] : 0.f;
  }
  { int gx = x0 + t; xs[t][30] = (gx < X) ? gg[(size_t)b * X + gx] : 0.f; }
  __syncthreads();
  int gx = x0 + t;
  if (gx >= XP) return;
  if (gx >= X){
    for (int c = 0; c < W; ++c) h[((size_t)b * W + c) * XP + gx] = 0.f;
    return;
  }
  for (int c = 0; c < W; ++c){
    float a = bg[c];
    #pragma unroll
    for (int f = 0; f < NIN; ++f) a = fmaf(wsh[c][f], xs[t][f], a);
    h[((size_t)b * W + c) * XP + gx] = a;
  }
}

// ---------------- gmid = gelu(W1 @ h + b1), bf16 out [b][o2][XPAD] ----------------
// MFMA: M=o2(128), N=x(128), K=c(64). A=w116 global, B=hT (LDS transpose of h).
__global__ __launch_bounds__(256) void k_gmid(const float* __restrict__ h,
                                              const short* __restrict__ w116,
                                              const float* __restrict__ b1g,
                                              short* __restrict__ gmid16, int blk){
  __shared__ short hT[128][72];   // [x][c], rows 144B
  int b = blockIdx.y, x0 = blockIdx.x * 128, t = threadIdx.x;
  int w = t >> 6, l = t & 63, q = l >> 4, ln = l & 15;
  for (int i = t; i < 4096; i += 256){
    int x = i & 127, cp = i >> 7;
    int gx = x0 + x;
    float v0 = 0.f, v1 = 0.f;
    if (gx < XP){
      v0 = h[((size_t)b * W + 2 * cp)     * XP + gx];
      v1 = h[((size_t)b * W + 2 * cp + 1) * XP + gx];
    }
    hT[x][2 * cp]     = f2bs(v0);
    hT[x][2 * cp + 1] = f2bs(v1);
  }
  __syncthreads();
  floatx4 acc[2][8];
  #pragma unroll
  for (int mt = 0; mt < 2; ++mt)
    #pragma unroll
    for (int nt = 0; nt < 8; ++nt) acc[mt][nt] = (floatx4){0.f,0.f,0.f,0.f};
  #pragma unroll
  for (int ks = 0; ks < 2; ++ks){
    short8 a0 = *(const short8*)&w116[((size_t)blk * H + (w*2+0)*16 + ln) * 64 + ks*32 + q*8];
    short8 a1 = *(const short8*)&w116[((size_t)blk * H + (w*2+1)*16 + ln) * 64 + ks*32 + q*8];
    #pragma unroll
    for (int nt = 0; nt < 8; ++nt){
      short8 bv = *(const short8*)&hT[nt*16 + ln][ks*32 + q*8];
      acc[0][nt] = MFMA(a0, bv, acc[0][nt]);
      acc[1][nt] = MFMA(a1, bv, acc[1][nt]);
    }
  }
  #pragma unroll
  for (int mt = 0; mt < 2; ++mt){
    float bvv[4];
    #pragma unroll
    for (int r = 0; r < 4; ++r) bvv[r] = b1g[blk * H + (w*2+mt)*16 + q*4 + r];
    #pragma unroll
    for (int nt = 0; nt < 8; ++nt){
      int gx = x0 + nt*16 + ln;
      #pragma unroll
      for (int r = 0; r < 4; ++r){
        int o2 = (w*2+mt)*16 + q*4 + r;
        float vv = gelu_f(acc[mt][nt][r] + bvv[r]);
        gmid16[((size_t)b * H + o2) * XPAD + gx] = (gx < XP) ? f2bs(vv) : (short)0;
      }
    }
  }
}

// ---------------- DFT (64 modes), MFMA split-K, fp32 atomics ----------------
// z=0: h (LDS-staged bf16); z=1/2: gmid16 halves (direct global).
// C[c][mp] = sum_x src[c][x]*basT16[mp][x]; im rows negated in epilogue.
__global__ __launch_bounds__(256) void k_dft(const float* __restrict__ h,
                                             const short* __restrict__ gmid16,
                                             const short* __restrict__ basT16,
                                             float* __restrict__ vhat,
                                             float* __restrict__ gmidhat){
  __shared__ short sT[64][136];
  int b = blockIdx.y, z = blockIdx.z;
  int xb = blockIdx.x * 1024, t = threadIdx.x;
  int w = t >> 6, l = t & 63, q = l >> 4, ln = l & 15;
  floatx4 acc[8];
  #pragma unroll
  for (int i = 0; i < 8; ++i) acc[i] = (floatx4){0.f,0.f,0.f,0.f};
  for (int xc = xb; xc < xb + 1024 && xc < XPAD; xc += 128){
    if (z == 0){
      __syncthreads();
      for (int i = t; i < 1024; i += 256){
        int c = i & 63, x8 = (i >> 6) * 8;
        const float* hp = h + ((size_t)b * W + c) * XP;
        short* dp = &sT[c][x8];
        #pragma unroll
        for (int j = 0; j < 8; ++j){
          int gx = xc + x8 + j;
          dp[j] = f2bs((gx < XP) ? hp[gx] : 0.f);
        }
      }
      __syncthreads();
    }
    #pragma unroll
    for (int ks = 0; ks < 4; ++ks){
      short8 av;
      if (z == 0) av = *(const short8*)&sT[w*16 + ln][ks*32 + q*8];
      else av = *(const short8*)&gmid16[((size_t)b * H + (z-1)*64 + w*16 + ln) * XPAD + xc + ks*32 + q*8];
      #pragma unroll
      for (int nt = 0; nt < 8; ++nt){
        short8 bv = *(const short8*)&basT16[(size_t)(nt*16 + ln) * XPAD + xc + ks*32 + q*8];
        acc[nt] = MFMA(av, bv, acc[nt]);
      }
    }
  }
  #pragma unroll
  for (int nt = 0; nt < 8; ++nt)
    #pragma unroll
    for (int r = 0; r < 4; ++r){
      int mp = nt*16 + ln;
      int c  = w*16 + q*4 + r;
      float v = acc[nt][r];
      if (mp & 1) v = -v;                    // im = -sum(src*sin)
      if (z == 0) atomicAdd(&vhat[((size_t)b * W + c) * 128 + mp], v);
      else atomicAdd(&gmidhat[((size_t)b * H + (z-1)*64 + c) * 128 + mp], v);
    }
}

// ---------------- ghat = ag*(W2 @ gmidhat) + ag*b2*XP at m=0 (fp32 VALU) ----------------
__global__ __launch_bounds__(256) void k_ghat(const float* __restrict__ gmidhat,
                                              const float* __restrict__ w2g,
                                              const float* __restrict__ b2g,
                                              const float* __restrict__ agr,
                                              float* __restrict__ ghat, int blk){
  __shared__ float w2s[64][133];
  int b = blockIdx.x, t = threadIdx.x;
  float ag = softplus_f(agr[0]);
  for (int i = t; i < 8192; i += 256) w2s[i >> 7][i & 127] = w2g[(size_t)blk * 8192 + i];
  __syncthreads();
  int i = t & 63, mg = t >> 6;
  for (int mp = mg * 32; mp < mg * 32 + 32; ++mp){
    float acc = 0.f;
    for (int c2 = 0; c2 < H; ++c2)
      acc = fmaf(w2s[i][c2], gmidhat[((size_t)b * H + c2) * 128 + mp], acc);
    if (mp == 0) acc += (float)XP * b2g[blk * W + i];
    ghat[((size_t)b * W + i) * 128 + mp] = ag * acc;
  }
}

// ---------------- out_m (fp32 VALU, proven round-3 kernel; bf16 output) ----------------
__global__ void k_outm(const float* __restrict__ vhat, const float* __restrict__ ghat,
                       const float* __restrict__ mix_re, const float* __restrict__ mix_im,
                       const float* __restrict__ expz, const float* __restrict__ phi,
                       const float* __restrict__ filt, short* __restrict__ outm16, int blk){
  int b = blockIdx.y, o = blockIdx.x, m = threadIdx.x;
  const float* mre = mix_re + (size_t)blk * W * W * M + (size_t)o * M + m;
  const float* mim = mix_im + (size_t)blk * W * W * M + (size_t)o * M + m;
  float gr = 0.f, gi = 0.f;
  for (int i = 0; i < W; ++i){
    float gre = ghat[((size_t)b * W + i) * 128 + 2 * m];
    float gim = ghat[((size_t)b * W + i) * 128 + 2 * m + 1];
    float xr = mre[(size_t)i * W * M];
    float xi = mim[(size_t)i * W * M];
    gr = fmaf(gre, xr, gr); gr = fmaf(-gim, xi, gr);
    gi = fmaf(gre, xi, gi); gi = fmaf( gim, xr, gi);
  }
  int om = blk * W * M + o * M + m;
  float ez = expz[om], ph = phi[om], fl = filt[m];
  float vr = vhat[((size_t)b * W + o) * 128 + 2 * m];
  float vi = vhat[((size_t)b * W + o) * 128 + 2 * m + 1];
  float outr = fmaf(ez, vr, ph * fl * gr);
  float outi = fmaf(ez, vi, ph * fl * gi);
  float sc = ((m == 0) ? 1.0f : 2.0f) / (float)XP;   // fold irfft scaling
  outm16[((size_t)b * W + o) * 128 + 2 * m]     = f2bs(outr * sc);
  outm16[((size_t)b * W + o) * 128 + 2 * m + 1] = f2bs(outi * sc);
}

// ---------------- update: h = act(iDFT(out_m) + aw*(W h + b)), MFMA flipped ----------------
// C[x][o] = sum_kp basC16[x][kp]*om[o][kp] + sum_c hT[x][c]*(aw*ww)[o][c]
__global__ __launch_bounds__(256) void k_update(float* __restrict__ h,
                                                const short* __restrict__ outm16,
                                                const short* __restrict__ basC16,
                                                const short* __restrict__ ww16,
                                                const float* __restrict__ wbg,
                                                const float* __restrict__ awr, int blk){
  __shared__ short hT[128][72];
  int b = blockIdx.y, x0 = blockIdx.x * 128, t = threadIdx.x;
  int w = t >> 6, l = t & 63, q = l >> 4, ln = l & 15;
  float aw = softplus_f(awr[0]);
  for (int i = t; i < 4096; i += 256){
    int x = i & 127, cp = i >> 7;
    int gx = x0 + x;
    float v0 = 0.f, v1 = 0.f;
    if (gx < XP){
      v0 = h[((size_t)b * W + 2 * cp)     * XP + gx];
      v1 = h[((size_t)b * W + 2 * cp + 1) * XP + gx];
    }
    hT[x][2 * cp]     = f2bs(v0);
    hT[x][2 * cp + 1] = f2bs(v1);
  }
  __syncthreads();
  floatx4 acc[2][4];
  #pragma unroll
  for (int mt = 0; mt < 2; ++mt)
    #pragma unroll
    for (int nt = 0; nt < 4; ++nt) acc[mt][nt] = (floatx4){0.f,0.f,0.f,0.f};
  #pragma unroll
  for (int ks = 0; ks < 4; ++ks){                 // etd: K=128 (kp)
    short8 a0 = *(const short8*)&basC16[(size_t)(x0 + (w*2+0)*16 + ln) * 128 + ks*32 + q*8];
    short8 a1 = *(const short8*)&basC16[(size_t)(x0 + (w*2+1)*16 + ln) * 128 + ks*32 + q*8];
    #pragma unroll
    for (int nt = 0; nt < 4; ++nt){
      short8 bv = *(const short8*)&outm16[((size_t)b * W + nt*16 + ln) * 128 + ks*32 + q*8];
      acc[0][nt] = MFMA(a0, bv, acc[0][nt]);
      acc[1][nt] = MFMA(a1, bv, acc[1][nt]);
    }
  }
  #pragma unroll
  for (int ks = 0; ks < 2; ++ks){                 // aw*W@h: K=64 (c)
    short8 a0 = *(const short8*)&hT[(w*2+0)*16 + ln][ks*32 + q*8];
    short8 a1 = *(const short8*)&hT[(w*2+1)*16 + ln][ks*32 + q*8];
    #pragma unroll
    for (int nt = 0; nt < 4; ++nt){
      short8 bv = *(const short8*)&ww16[((size_t)blk * W + nt*16 + ln) * 64 + ks*32 + q*8];
      acc[0][nt] = MFMA(a0, bv, acc[0][nt]);
      acc[1][nt] = MFMA(a1, bv, acc[1][nt]);
    }
  }
  #pragma unroll
  for (int mt = 0; mt < 2; ++mt)
    #pragma unroll
    for (int nt = 0; nt < 4; ++nt){
      int o = nt*16 + ln;
      int xbase = x0 + (w*2+mt)*16 + q*4;
      float wbv = aw * wbg[blk * W + o];
      float* hp = &h[((size_t)b * W + o) * XP + xbase];
      #pragma unroll
      for (int r = 0; r < 4; ++r){
        if (xbase + r < XP){
          float u = acc[mt][nt][r] + wbv;
          if (blk != NB - 1) u = gelu_f(u);
          hp[r] = u;
        }
      }
    }
}

// ---------------- fc12: MFMA fc1 (M=o 128, N=x 128, K=64) + VALU fc2 ----------------
__global__ __launch_bounds__(256) void k_fc12(const float* __restrict__ h,
                                              const short* __restrict__ w1fc16,
                                              const float* __restrict__ b1,
                                              const float* __restrict__ w2,
                                              const float* __restrict__ b2,
                                              float* __restrict__ out){
  __shared__ short hT[128][72];
  __shared__ short gT[128][136];
  __shared__ float w2s[NC][132];
  __shared__ float red[2][128][NC];
  int b = blockIdx.y, x0 = blockIdx.x * 128, t = threadIdx.x;
  int w = t >> 6, l = t & 63, q = l >> 4, ln = l & 15;
  for (int i = t; i < 4096; i += 256){
    int x = i & 127, cp = i >> 7;
    int gx = x0 + x;                       // < X always
    hT[x][2 * cp]     = f2bs(h[((size_t)b * W + 2 * cp)     * XP + gx]);
    hT[x][2 * cp + 1] = f2bs(h[((size_t)b * W + 2 * cp + 1) * XP + gx]);
  }
  for (int i = t; i < NC * H; i += 256) w2s[i / H][i % H] = w2[i];
  __syncthreads();
  floatx4 acc[2][8];
  #pragma unroll
  for (int mt = 0; mt < 2; ++mt)
    #pragma unroll
    for (int nt = 0; nt < 8; ++nt) acc[mt][nt] = (floatx4){0.f,0.f,0.f,0.f};
  #pragma unroll
  for (int ks = 0; ks < 2; ++ks){
    short8 a0 = *(const short8*)&w1fc16[(size_t)((w*2+0)*16 + ln) * 64 + ks*32 + q*8];
    short8 a1 = *(const short8*)&w1fc16[(size_t)((w*2+1)*16 + ln) * 64 + ks*32 + q*8];
    #pragma unroll
    for (int nt = 0; nt < 8; ++nt){
      short8 bv = *(const short8*)&hT[nt*16 + ln][ks*32 + q*8];
      acc[0][nt] = MFMA(a0, bv, acc[0][nt]);
      acc[1][nt] = MFMA(a1, bv, acc[1][nt]);
    }
  }
  #pragma unroll
  for (int mt = 0; mt < 2; ++mt){
    float bvv[4];
    #pragma unroll
    for (int r = 0; r < 4; ++r) bvv[r] = b1[(w*2+mt)*16 + q*4 + r];
    #pragma unroll
    for (int nt = 0; nt < 8; ++nt){
      int x = nt*16 + ln;
      #pragma unroll
      for (int r = 0; r < 4; ++r)
        gT[x][(w*2+mt)*16 + q*4 + r] = f2bs(gelu_f(acc[mt][nt][r] + bvv[r]));
    }
  }
  __syncthreads();
  int x = t & 127, half = t >> 7;
  float a3[NC] = {0.f, 0.f, 0.f};
  for (int og = 0; og < 8; ++og){
    int o0 = half * 64 + og * 8;
    short8 gv = *(const short8*)&gT[x][o0];
    #pragma unroll
    for (int j = 0; j < 8; ++j){
      float gf = bs2f(gv[j]);
      #pragma unroll
      for (int n = 0; n < NC; ++n) a3[n] = fmaf(gf, w2s[n][o0 + j], a3[n]);
    }
  }
  #pragma unroll
  for (int n = 0; n < NC; ++n) red[half][x][n] = a3[n];
  __syncthreads();
  if (half == 0){
    #pragma unroll
    for (int n = 0; n < NC; ++n)
      out[((size_t)b * X + x0 + x) * NC + n] = red[0][x][n] + red[1][x][n] + b2[n];
  }
}

extern "C" void kernel_launch(void* const* d_in, const int* in_sizes, int n_in,
                              void* d_out, int out_size, void* d_ws, size_t ws_size,
                              hipStream_t stream){
  (void)in_sizes; (void)n_in; (void)out_size; (void)ws_size;
  const float* x        = (const float*)d_in[0];
  const float* grid     = (const float*)d_in[1];
  const float* fc0_w    = (const float*)d_in[2];
  const float* fc0_b    = (const float*)d_in[3];
  const float* fc1_w    = (const float*)d_in[4];
  const float* fc1_b    = (const float*)d_in[5];
  const float* fc2_w    = (const float*)d_in[6];
  const float* fc2_b    = (const float*)d_in[7];
  const float* g_w1     = (const float*)d_in[8];
  const float* g_b1     = (const float*)d_in[9];
  const float* g_w2     = (const float*)d_in[10];
  const float* g_b2     = (const float*)d_in[11];
  const float* w_w      = (const float*)d_in[12];
  const float* w_b      = (const float*)d_in[13];
  const float* log_dec  = (const float*)d_in[14];
  const float* mix_re   = (const float*)d_in[15];
  const float* mix_im   = (const float*)d_in[16];
  const float* a_w      = (const float*)d_in[17];
  const float* a_g      = (const float*)d_in[18];
  float* out = (float*)d_out;

  // workspace carve (bytes ~145.8MB; all 16B aligned)
  short* basC16 = (short*)d_ws;                    // 16512*128
  short* basT16 = basC16 + (size_t)XPAD * 128;     // 128*16512
  float* h      = (float*)(basT16 + (size_t)128 * XPAD);
  short* gmid16 = (short*)(h + (size_t)BB * W * XP);          // 16*128*16512
  float* vhat   = (float*)(gmid16 + (size_t)BB * H * XPAD);   // 16*64*128
  float* gmidhat= vhat + (size_t)BB * W * 128;                // 16*128*128
  float* ghat   = gmidhat + (size_t)BB * H * 128;             // 16*64*128
  float* expz   = ghat + (size_t)BB * W * 128;
  float* phi    = expz + NB * W * M;
  float* filt   = phi + NB * W * M;
  short* outm16 = (short*)(filt + 64);             // 16*64*128
  short* ww16   = outm16 + (size_t)BB * W * 128;   // 4*64*64
  short* w116   = ww16 + NB * W * W;               // 4*128*64
  short* w1fc16 = w116 + NB * H * W;               // 128*64

  k_basis<<<dim3((XPAD * M + 255) / 256), 256, 0, stream>>>(basT16, basC16);
  k_decay<<<dim3((NB * W * M + 255) / 256), 256, 0, stream>>>(log_dec, expz, phi);
  k_filt<<<1, 64, 0, stream>>>(filt);
  k_prep<<<dim3(224), 256, 0, stream>>>(w_w, g_w1, fc1_w, a_w, ww16, w116, w1fc16);
  k_fc0<<<dim3((XP + 255) / 256, BB), 256, 0, stream>>>(x, grid, fc0_w, fc0_b, h);

  for (int blk = 0; blk < NB; ++blk){
    k_gmid<<<dim3(XPAD / 128, BB), 256, 0, stream>>>(h, w116, g_b1, gmid16, blk);
    hipMemsetAsync(vhat, 0, (size_t)(BB * W * 128 + BB * H * 128) * sizeof(float), stream);
    k_dft<<<dim3(17, BB, 3), 256, 0, stream>>>(h, gmid16, basT16, vhat, gmidhat);
    k_ghat<<<dim3(BB), 256, 0, stream>>>(gmidhat, g_w2, g_b2, a_g, ghat, blk);
    k_outm<<<dim3(W, BB), 64, 0, stream>>>(vhat, ghat, mix_re, mix_im, expz, phi, filt, outm16, blk);
    k_update<<<dim3(XPAD / 128, BB), 256, 0, stream>>>(h, outm16, basC16, ww16, w_b, a_w, blk);
  }
  k_fc12<<<dim3(X / 128, BB), 256, 0, stream>>>(h, w1fc16, fc1_b, fc2_w, fc2_b, out);
}

// Round 5
// 1195.175 us; speedup vs baseline: 3.7419x; 1.4573x over previous
//
#include <hip/hip_runtime.h>
#include <hip/hip_bf16.h>

// SGNO1d: B=16, X=16384, Xp=16386, W=64, H=128, M=64, NB=4.
// MFMA bf16 rewrite. Key identities:
//  - only 64 modes survive -> rfft/irfft are dense DFT GEMMs (K=16386 / K=128)
//  - DFT linearity: ghat = ag*(W2 @ DFT(gmid) + b2*XP*delta_m0)  -> g never materialized
// R5: k_dft/k_update operands staged via LDS with coalesced global loads
// (R4 read MFMA fragments straight from global -> 64-segment gathers, latency-bound).

#define BB 16
#define X 16384
#define XP 16386
#define XPAD 16512   // 129*128, zero-padded tail for tile-uniform MFMA
#define W 64
#define H 128
#define M 64
#define NB 4
#define NIN 31
#define NC 3

typedef __hip_bfloat16 bf16;
typedef __attribute__((ext_vector_type(8))) short short8;
typedef __attribute__((ext_vector_type(4))) float floatx4;

__device__ __forceinline__ float gelu_f(float t){
  return 0.5f * t * (1.0f + erff(t * 0.70710678118654752440f));
}
__device__ __forceinline__ float softplus_f(float v){
  return (v > 20.f) ? v : log1pf(expf(v));
}
__device__ __forceinline__ short f2bs(float f){   // fp32 -> bf16 bits (RNE)
  union { float f; unsigned u; } v; v.f = f;
  unsigned r = (v.u + 0x7FFFu + ((v.u >> 16) & 1u)) >> 16;
  return (short)r;
}
__device__ __forceinline__ float bs2f(short s){
  union { unsigned u; float f; } v; v.u = ((unsigned)(unsigned short)s) << 16;
  return v.f;
}
#define MFMA(a,b,c) __builtin_amdgcn_mfma_f32_16x16x32_bf16((a),(b),(c),0,0,0)

// ---------------- precompute: two bf16 DFT bases ----------------
// basT16[mp][x]  (mp=2m:cos, 2m+1:+sin), rows along x   -> DFT B-operand
// basC16[x][kp]  (kp=2m:cos, 2m+1:-sin), rows along kp  -> iDFT A-operand
__global__ __launch_bounds__(256) void k_basis(short* __restrict__ basT16,
                                               short* __restrict__ basC16){
  int idx = blockIdx.x * 256 + threadIdx.x;
  if (idx >= XPAD * M) return;
  int x = idx >> 6, m = idx & 63;
  short cb = 0, sb = 0, nsb = 0;
  if (x < XP){
    int tt = (int)(((long long)x * (long long)m) % XP);
    float ang = 6.283185307179586477f * (float)tt / (float)XP;
    float s, c; sincosf(ang, &s, &c);
    cb = f2bs(c); sb = f2bs(s); nsb = f2bs(-s);
  }
  basT16[(size_t)(2*m)   * XPAD + x] = cb;
  basT16[(size_t)(2*m+1) * XPAD + x] = sb;
  basC16[(size_t)x * 128 + 2*m]     = cb;
  basC16[(size_t)x * 128 + 2*m + 1] = nsb;
}

__global__ __launch_bounds__(256) void k_decay(const float* __restrict__ log_decay,
                                               float* __restrict__ expz,
                                               float* __restrict__ phi){
  int idx = blockIdx.x * 256 + threadIdx.x;
  if (idx >= NB * W * M) return;
  float z = -softplus_f(log_decay[idx]);
  expz[idx] = expf(z);
  float p;
  if (fabsf(z) < 1e-6f) p = 1.0f + 0.5f * z + z * z * (1.0f / 6.0f);
  else                  p = expm1f(z) / z;
  phi[idx] = p;
}

__global__ void k_filt(float* __restrict__ filt){
  int m = threadIdx.x;
  if (m < M){
    float g = (float)m / 63.0f;
    float r2 = g * g + 1e-12f;
    float r4 = r2 * r2;
    float r8 = r4 * r4;
    filt[m] = expf(-2.0f * r8);
  }
}

// bf16 weight copies: ww16 = aw*w_w, w116 = g_w1, w1fc16 = fc1_w (all rows along c=K)
__global__ __launch_bounds__(256) void k_prep(const float* __restrict__ w_w,
                                              const float* __restrict__ g_w1,
                                              const float* __restrict__ fc1_w,
                                              const float* __restrict__ awr,
                                              short* __restrict__ ww16,
                                              short* __restrict__ w116,
                                              short* __restrict__ w1fc16){
  int idx = blockIdx.x * 256 + threadIdx.x;
  float aw = softplus_f(awr[0]);
  if (idx < 16384){ ww16[idx] = f2bs(aw * w_w[idx]); }
  else if (idx < 49152){ int i = idx - 16384; w116[i] = f2bs(g_w1[i]); }
  else if (idx < 57344){ int i = idx - 49152; w1fc16[i] = f2bs(fc1_w[i]); }
}

// ---------------- fc0 (unchanged, VALU) ----------------
__global__ __launch_bounds__(256) void k_fc0(const float* __restrict__ xg,
                                             const float* __restrict__ gg,
                                             const float* __restrict__ wg,
                                             const float* __restrict__ bg,
                                             float* __restrict__ h){
  __shared__ float xs[256][33];
  __shared__ float wsh[W][NIN];
  int b = blockIdx.y, x0 = blockIdx.x * 256, t = threadIdx.x;
  for (int i = t; i < W * NIN; i += 256) wsh[i / NIN][i % NIN] = wg[i];
  for (int i = t; i < 256 * 30; i += 256){
    int p = i / 30, f = i - p * 30, gx = x0 + p;
    xs[p][f] = (gx < X) ? xg[((size_t)b * X + gx) * 30 + f] : 0.f;
  }
  { int gx = x0 + t; xs[t][30] = (gx < X) ? gg[(size_t)b * X + gx] : 0.f; }
  __syncthreads();
  int gx = x0 + t;
  if (gx >= XP) return;
  if (gx >= X){
    for (int c = 0; c < W; ++c) h[((size_t)b * W + c) * XP + gx] = 0.f;
    return;
  }
  for (int c = 0; c < W; ++c){
    float a = bg[c];
    #pragma unroll
    for (int f = 0; f < NIN; ++f) a = fmaf(wsh[c][f], xs[t][f], a);
    h[((size_t)b * W + c) * XP + gx] = a;
  }
}

// ---------------- gmid = gelu(W1 @ h + b1), bf16 out [b][o2][XPAD] ----------------
__global__ __launch_bounds__(256) void k_gmid(const float* __restrict__ h,
                                              const short* __restrict__ w116,
                                              const float* __restrict__ b1g,
                                              short* __restrict__ gmid16, int blk){
  __shared__ short hT[128][72];   // [x][c]
  int b = blockIdx.y, x0 = blockIdx.x * 128, t = threadIdx.x;
  int w = t >> 6, l = t & 63, q = l >> 4, ln = l & 15;
  for (int i = t; i < 4096; i += 256){
    int x = i & 127, cp = i >> 7;
    int gx = x0 + x;
    float v0 = 0.f, v1 = 0.f;
    if (gx < XP){
      v0 = h[((size_t)b * W + 2 * cp)     * XP + gx];
      v1 = h[((size_t)b * W + 2 * cp + 1) * XP + gx];
    }
    hT[x][2 * cp]     = f2bs(v0);
    hT[x][2 * cp + 1] = f2bs(v1);
  }
  __syncthreads();
  floatx4 acc[2][8];
  #pragma unroll
  for (int mt = 0; mt < 2; ++mt)
    #pragma unroll
    for (int nt = 0; nt < 8; ++nt) acc[mt][nt] = (floatx4){0.f,0.f,0.f,0.f};
  #pragma unroll
  for (int ks = 0; ks < 2; ++ks){
    short8 a0 = *(const short8*)&w116[((size_t)blk * H + (w*2+0)*16 + ln) * 64 + ks*32 + q*8];
    short8 a1 = *(const short8*)&w116[((size_t)blk * H + (w*2+1)*16 + ln) * 64 + ks*32 + q*8];
    #pragma unroll
    for (int nt = 0; nt < 8; ++nt){
      short8 bv = *(const short8*)&hT[nt*16 + ln][ks*32 + q*8];
      acc[0][nt] = MFMA(a0, bv, acc[0][nt]);
      acc[1][nt] = MFMA(a1, bv, acc[1][nt]);
    }
  }
  #pragma unroll
  for (int mt = 0; mt < 2; ++mt){
    float bvv[4];
    #pragma unroll
    for (int r = 0; r < 4; ++r) bvv[r] = b1g[blk * H + (w*2+mt)*16 + q*4 + r];
    #pragma unroll
    for (int nt = 0; nt < 8; ++nt){
      int gx = x0 + nt*16 + ln;
      #pragma unroll
      for (int r = 0; r < 4; ++r){
        int o2 = (w*2+mt)*16 + q*4 + r;
        float vv = gelu_f(acc[mt][nt][r] + bvv[r]);
        gmid16[((size_t)b * H + o2) * XPAD + gx] = (gx < XP) ? f2bs(vv) : (short)0;
      }
    }
  }
}

// ---------------- DFT (64 modes), MFMA split-K, LDS-staged operands ----------------
// z=0: h rows; z=1/2: gmid16 halves. C[c][mp] = sum_x src[c][x]*basT16[mp][x].
__global__ __launch_bounds__(256) void k_dft(const float* __restrict__ h,
                                             const short* __restrict__ gmid16,
                                             const short* __restrict__ basT16,
                                             float* __restrict__ vhat,
                                             float* __restrict__ gmidhat){
  __shared__ short srcT[64][136];    // 17.4 KB
  __shared__ short basS[128][136];   // 34.8 KB
  int b = blockIdx.y, z = blockIdx.z;
  int xb = blockIdx.x * 1024, t = threadIdx.x;
  int w = t >> 6, l = t & 63, q = l >> 4, ln = l & 15;
  floatx4 acc[8];
  #pragma unroll
  for (int i = 0; i < 8; ++i) acc[i] = (floatx4){0.f,0.f,0.f,0.f};
  for (int xc = xb; xc < xb + 1024 && xc < XPAD; xc += 128){
    __syncthreads();
    if (z == 0){
      int c = t >> 2, seg = (t & 3) * 32;
      const float* hp = h + ((size_t)b * W + c) * XP + xc + seg;
      if (xc + 128 <= XP){
        #pragma unroll
        for (int j = 0; j < 8; ++j){
          float4 v = *(const float4*)(hp + j * 4);
          srcT[c][seg + j*4 + 0] = f2bs(v.x);
          srcT[c][seg + j*4 + 1] = f2bs(v.y);
          srcT[c][seg + j*4 + 2] = f2bs(v.z);
          srcT[c][seg + j*4 + 3] = f2bs(v.w);
        }
      } else {
        for (int j = 0; j < 32; ++j){
          int gx = xc + seg + j;
          srcT[c][seg + j] = (gx < XP) ? f2bs(hp[j]) : (short)0;
        }
      }
    } else {
      const short* gp = gmid16 + ((size_t)b * H + (z - 1) * 64) * XPAD + xc;
      #pragma unroll
      for (int u = 0; u < 4; ++u){
        int idx = u * 256 + t;          // 0..1023
        int c = idx >> 4, col = (idx & 15) * 8;
        *(short8*)&srcT[c][col] = *(const short8*)&gp[(size_t)c * XPAD + col];
      }
    }
    #pragma unroll
    for (int u = 0; u < 8; ++u){
      int idx = u * 256 + t;            // 0..2047
      int mp = idx >> 4, col = (idx & 15) * 8;
      *(short8*)&basS[mp][col] = *(const short8*)&basT16[(size_t)mp * XPAD + xc + col];
    }
    __syncthreads();
    #pragma unroll
    for (int ks = 0; ks < 4; ++ks){
      short8 av = *(const short8*)&srcT[w*16 + ln][ks*32 + q*8];
      #pragma unroll
      for (int nt = 0; nt < 8; ++nt){
        short8 bv = *(const short8*)&basS[nt*16 + ln][ks*32 + q*8];
        acc[nt] = MFMA(av, bv, acc[nt]);
      }
    }
  }
  #pragma unroll
  for (int nt = 0; nt < 8; ++nt)
    #pragma unroll
    for (int r = 0; r < 4; ++r){
      int mp = nt*16 + ln;
      int c  = w*16 + q*4 + r;
      float v = acc[nt][r];
      if (mp & 1) v = -v;                    // im = -sum(src*sin)
      if (z == 0) atomicAdd(&vhat[((size_t)b * W + c) * 128 + mp], v);
      else atomicAdd(&gmidhat[((size_t)b * H + (z-1)*64 + c) * 128 + mp], v);
    }
}

// ---------------- ghat = ag*(W2 @ gmidhat) + ag*b2*XP at m=0 (fp32 VALU) ----------------
__global__ __launch_bounds__(256) void k_ghat(const float* __restrict__ gmidhat,
                                              const float* __restrict__ w2g,
                                              const float* __restrict__ b2g,
                                              const float* __restrict__ agr,
                                              float* __restrict__ ghat, int blk){
  __shared__ float w2s[64][133];
  int b = blockIdx.x, t = threadIdx.x;
  float ag = softplus_f(agr[0]);
  for (int i = t; i < 8192; i += 256) w2s[i >> 7][i & 127] = w2g[(size_t)blk * 8192 + i];
  __syncthreads();
  int i = t & 63, mg = t >> 6;
  for (int mp = mg * 32; mp < mg * 32 + 32; ++mp){
    float acc = 0.f;
    for (int c2 = 0; c2 < H; ++c2)
      acc = fmaf(w2s[i][c2], gmidhat[((size_t)b * H + c2) * 128 + mp], acc);
    if (mp == 0) acc += (float)XP * b2g[blk * W + i];
    ghat[((size_t)b * W + i) * 128 + mp] = ag * acc;
  }
}

// ---------------- out_m (fp32 VALU; bf16 output) ----------------
__global__ void k_outm(const float* __restrict__ vhat, const float* __restrict__ ghat,
                       const float* __restrict__ mix_re, const float* __restrict__ mix_im,
                       const float* __restrict__ expz, const float* __restrict__ phi,
                       const float* __restrict__ filt, short* __restrict__ outm16, int blk){
  int b = blockIdx.y, o = blockIdx.x, m = threadIdx.x;
  const float* mre = mix_re + (size_t)blk * W * W * M + (size_t)o * M + m;
  const float* mim = mix_im + (size_t)blk * W * W * M + (size_t)o * M + m;
  float gr = 0.f, gi = 0.f;
  for (int i = 0; i < W; ++i){
    float gre = ghat[((size_t)b * W + i) * 128 + 2 * m];
    float gim = ghat[((size_t)b * W + i) * 128 + 2 * m + 1];
    float xr = mre[(size_t)i * W * M];
    float xi = mim[(size_t)i * W * M];
    gr = fmaf(gre, xr, gr); gr = fmaf(-gim, xi, gr);
    gi = fmaf(gre, xi, gi); gi = fmaf( gim, xr, gi);
  }
  int om = blk * W * M + o * M + m;
  float ez = expz[om], ph = phi[om], fl = filt[m];
  float vr = vhat[((size_t)b * W + o) * 128 + 2 * m];
  float vi = vhat[((size_t)b * W + o) * 128 + 2 * m + 1];
  float outr = fmaf(ez, vr, ph * fl * gr);
  float outi = fmaf(ez, vi, ph * fl * gi);
  float sc = ((m == 0) ? 1.0f : 2.0f) / (float)XP;   // fold irfft scaling
  outm16[((size_t)b * W + o) * 128 + 2 * m]     = f2bs(outr * sc);
  outm16[((size_t)b * W + o) * 128 + 2 * m + 1] = f2bs(outi * sc);
}

// ---------------- update: h = act(iDFT(out_m) + aw*(W h + b)), two-phase LDS ----------------
// C[x][o] = sum_kp basC16[x][kp]*om[o][kp] + sum_c hT[x][c]*(aw*ww)[o][c]
__global__ __launch_bounds__(256) void k_update(float* __restrict__ h,
                                                const short* __restrict__ outm16,
                                                const short* __restrict__ basC16,
                                                const short* __restrict__ ww16,
                                                const float* __restrict__ wbg,
                                                const float* __restrict__ awr, int blk){
  __shared__ __align__(16) char smem[52224];
  short (*hT)[72]    = (short(*)[72])smem;             // phase1: 128x72 (18.4 KB)
  short (*wwS)[72]   = (short(*)[72])(smem + 18432);   // phase1: 64x72  (9.2 KB)
  short (*basS)[136] = (short(*)[136])smem;            // phase2: 128x136 (34.8 KB)
  short (*omS)[136]  = (short(*)[136])(smem + 34816);  // phase2: 64x136  (17.4 KB)
  int b = blockIdx.y, x0 = blockIdx.x * 128, t = threadIdx.x;
  int w = t >> 6, l = t & 63, q = l >> 4, ln = l & 15;
  float aw = softplus_f(awr[0]);
  // ---- phase 1: hT + ww staging ----
  for (int i = t; i < 4096; i += 256){
    int x = i & 127, cp = i >> 7;
    int gx = x0 + x;
    float v0 = 0.f, v1 = 0.f;
    if (gx < XP){
      v0 = h[((size_t)b * W + 2 * cp)     * XP + gx];
      v1 = h[((size_t)b * W + 2 * cp + 1) * XP + gx];
    }
    hT[x][2 * cp]     = f2bs(v0);
    hT[x][2 * cp + 1] = f2bs(v1);
  }
  #pragma unroll
  for (int u = 0; u < 2; ++u){
    int idx = u * 256 + t;               // 0..511
    int o = idx >> 3, col = (idx & 7) * 8;
    *(short8*)&wwS[o][col] = *(const short8*)&ww16[((size_t)blk * W + o) * 64 + col];
  }
  __syncthreads();
  floatx4 acc[2][4];
  #pragma unroll
  for (int mt = 0; mt < 2; ++mt)
    #pragma unroll
    for (int nt = 0; nt < 4; ++nt) acc[mt][nt] = (floatx4){0.f,0.f,0.f,0.f};
  #pragma unroll
  for (int ks = 0; ks < 2; ++ks){                 // aw*W@h: K=64 (c)
    short8 a0 = *(const short8*)&hT[(w*2+0)*16 + ln][ks*32 + q*8];
    short8 a1 = *(const short8*)&hT[(w*2+1)*16 + ln][ks*32 + q*8];
    #pragma unroll
    for (int nt = 0; nt < 4; ++nt){
      short8 bv = *(const short8*)&wwS[nt*16 + ln][ks*32 + q*8];
      acc[0][nt] = MFMA(a0, bv, acc[0][nt]);
      acc[1][nt] = MFMA(a1, bv, acc[1][nt]);
    }
  }
  __syncthreads();   // all phase-1 LDS reads done before overwrite
  // ---- phase 2: basC + outm staging ----
  #pragma unroll
  for (int u = 0; u < 8; ++u){
    int idx = u * 256 + t;               // 0..2047
    int x = idx >> 4, col = (idx & 15) * 8;
    *(short8*)&basS[x][col] = *(const short8*)&basC16[(size_t)(x0 + x) * 128 + col];
  }
  #pragma unroll
  for (int u = 0; u < 4; ++u){
    int idx = u * 256 + t;               // 0..1023
    int o = idx >> 4, col = (idx & 15) * 8;
    *(short8*)&omS[o][col] = *(const short8*)&outm16[((size_t)b * W + o) * 128 + col];
  }
  __syncthreads();
  #pragma unroll
  for (int ks = 0; ks < 4; ++ks){                 // etd: K=128 (kp)
    short8 a0 = *(const short8*)&basS[(w*2+0)*16 + ln][ks*32 + q*8];
    short8 a1 = *(const short8*)&basS[(w*2+1)*16 + ln][ks*32 + q*8];
    #pragma unroll
    for (int nt = 0; nt < 4; ++nt){
      short8 bv = *(const short8*)&omS[nt*16 + ln][ks*32 + q*8];
      acc[0][nt] = MFMA(a0, bv, acc[0][nt]);
      acc[1][nt] = MFMA(a1, bv, acc[1][nt]);
    }
  }
  #pragma unroll
  for (int mt = 0; mt < 2; ++mt)
    #pragma unroll
    for (int nt = 0; nt < 4; ++nt){
      int o = nt*16 + ln;
      int xbase = x0 + (w*2+mt)*16 + q*4;
      float wbv = aw * wbg[blk * W + o];
      float* hp = &h[((size_t)b * W + o) * XP + xbase];
      #pragma unroll
      for (int r = 0; r < 4; ++r){
        if (xbase + r < XP){
          float u = acc[mt][nt][r] + wbv;
          if (blk != NB - 1) u = gelu_f(u);
          hp[r] = u;
        }
      }
    }
}

// ---------------- fc12: MFMA fc1 (M=o 128, N=x 128, K=64) + VALU fc2 ----------------
__global__ __launch_bounds__(256) void k_fc12(const float* __restrict__ h,
                                              const short* __restrict__ w1fc16,
                                              const float* __restrict__ b1,
                                              const float* __restrict__ w2,
                                              const float* __restrict__ b2,
                                              float* __restrict__ out){
  __shared__ short hT[128][72];
  __shared__ short gT[128][136];
  __shared__ float w2s[NC][132];
  __shared__ float red[2][128][NC];
  int b = blockIdx.y, x0 = blockIdx.x * 128, t = threadIdx.x;
  int w = t >> 6, l = t & 63, q = l >> 4, ln = l & 15;
  for (int i = t; i < 4096; i += 256){
    int x = i & 127, cp = i >> 7;
    int gx = x0 + x;                       // < X always
    hT[x][2 * cp]     = f2bs(h[((size_t)b * W + 2 * cp)     * XP + gx]);
    hT[x][2 * cp + 1] = f2bs(h[((size_t)b * W + 2 * cp + 1) * XP + gx]);
  }
  for (int i = t; i < NC * H; i += 256) w2s[i / H][i % H] = w2[i];
  __syncthreads();
  floatx4 acc[2][8];
  #pragma unroll
  for (int mt = 0; mt < 2; ++mt)
    #pragma unroll
    for (int nt = 0; nt < 8; ++nt) acc[mt][nt] = (floatx4){0.f,0.f,0.f,0.f};
  #pragma unroll
  for (int ks = 0; ks < 2; ++ks){
    short8 a0 = *(const short8*)&w1fc16[(size_t)((w*2+0)*16 + ln) * 64 + ks*32 + q*8];
    short8 a1 = *(const short8*)&w1fc16[(size_t)((w*2+1)*16 + ln) * 64 + ks*32 + q*8];
    #pragma unroll
    for (int nt = 0; nt < 8; ++nt){
      short8 bv = *(const short8*)&hT[nt*16 + ln][ks*32 + q*8];
      acc[0][nt] = MFMA(a0, bv, acc[0][nt]);
      acc[1][nt] = MFMA(a1, bv, acc[1][nt]);
    }
  }
  #pragma unroll
  for (int mt = 0; mt < 2; ++mt){
    float bvv[4];
    #pragma unroll
    for (int r = 0; r < 4; ++r) bvv[r] = b1[(w*2+mt)*16 + q*4 + r];
    #pragma unroll
    for (int nt = 0; nt < 8; ++nt){
      int x = nt*16 + ln;
      #pragma unroll
      for (int r = 0; r < 4; ++r)
        gT[x][(w*2+mt)*16 + q*4 + r] = f2bs(gelu_f(acc[mt][nt][r] + bvv[r]));
    }
  }
  __syncthreads();
  int x = t & 127, half = t >> 7;
  float a3[NC] = {0.f, 0.f, 0.f};
  for (int og = 0; og < 8; ++og){
    int o0 = half * 64 + og * 8;
    short8 gv = *(const short8*)&gT[x][o0];
    #pragma unroll
    for (int j = 0; j < 8; ++j){
      float gf = bs2f(gv[j]);
      #pragma unroll
      for (int n = 0; n < NC; ++n) a3[n] = fmaf(gf, w2s[n][o0 + j], a3[n]);
    }
  }
  #pragma unroll
  for (int n = 0; n < NC; ++n) red[half][x][n] = a3[n];
  __syncthreads();
  if (half == 0){
    #pragma unroll
    for (int n = 0; n < NC; ++n)
      out[((size_t)b * X + x0 + x) * NC + n] = red[0][x][n] + red[1][x][n] + b2[n];
  }
}

extern "C" void kernel_launch(void* const* d_in, const int* in_sizes, int n_in,
                              void* d_out, int out_size, void* d_ws, size_t ws_size,
                              hipStream_t stream){
  (void)in_sizes; (void)n_in; (void)out_size; (void)ws_size;
  const float* x        = (const float*)d_in[0];
  const float* grid     = (const float*)d_in[1];
  const float* fc0_w    = (const float*)d_in[2];
  const float* fc0_b    = (const float*)d_in[3];
  const float* fc1_w    = (const float*)d_in[4];
  const float* fc1_b    = (const float*)d_in[5];
  const float* fc2_w    = (const float*)d_in[6];
  const float* fc2_b    = (const float*)d_in[7];
  const float* g_w1     = (const float*)d_in[8];
  const float* g_b1     = (const float*)d_in[9];
  const float* g_w2     = (const float*)d_in[10];
  const float* g_b2     = (const float*)d_in[11];
  const float* w_w      = (const float*)d_in[12];
  const float* w_b      = (const float*)d_in[13];
  const float* log_dec  = (const float*)d_in[14];
  const float* mix_re   = (const float*)d_in[15];
  const float* mix_im   = (const float*)d_in[16];
  const float* a_w      = (const float*)d_in[17];
  const float* a_g      = (const float*)d_in[18];
  float* out = (float*)d_out;

  // workspace carve (~145.8MB; all 16B aligned)
  short* basC16 = (short*)d_ws;                    // 16512*128
  short* basT16 = basC16 + (size_t)XPAD * 128;     // 128*16512
  float* h      = (float*)(basT16 + (size_t)128 * XPAD);
  short* gmid16 = (short*)(h + (size_t)BB * W * XP);          // 16*128*16512
  float* vhat   = (float*)(gmid16 + (size_t)BB * H * XPAD);   // 16*64*128
  float* gmidhat= vhat + (size_t)BB * W * 128;                // 16*128*128
  float* ghat   = gmidhat + (size_t)BB * H * 128;             // 16*64*128
  float* expz   = ghat + (size_t)BB * W * 128;
  float* phi    = expz + NB * W * M;
  float* filt   = phi + NB * W * M;
  short* outm16 = (short*)(filt + 64);             // 16*64*128
  short* ww16   = outm16 + (size_t)BB * W * 128;   // 4*64*64
  short* w116   = ww16 + NB * W * W;               // 4*128*64
  short* w1fc16 = w116 + NB * H * W;               // 128*64

  k_basis<<<dim3((XPAD * M + 255) / 256), 256, 0, stream>>>(basT16, basC16);
  k_decay<<<dim3((NB * W * M + 255) / 256), 256, 0, stream>>>(log_dec, expz, phi);
  k_filt<<<1, 64, 0, stream>>>(filt);
  k_prep<<<dim3(224), 256, 0, stream>>>(w_w, g_w1, fc1_w, a_w, ww16, w116, w1fc16);
  k_fc0<<<dim3((XP + 255) / 256, BB), 256, 0, stream>>>(x, grid, fc0_w, fc0_b, h);

  for (int blk = 0; blk < NB; ++blk){
    k_gmid<<<dim3(XPAD / 128, BB), 256, 0, stream>>>(h, w116, g_b1, gmid16, blk);
    hipMemsetAsync(vhat, 0, (size_t)(BB * W * 128 + BB * H * 128) * sizeof(float), stream);
    k_dft<<<dim3(17, BB, 3), 256, 0, stream>>>(h, gmid16, basT16, vhat, gmidhat);
    k_ghat<<<dim3(BB), 256, 0, stream>>>(gmidhat, g_w2, g_b2, a_g, ghat, blk);
    k_outm<<<dim3(W, BB), 64, 0, stream>>>(vhat, ghat, mix_re, mix_im, expz, phi, filt, outm16, blk);
    k_update<<<dim3(XPAD / 128, BB), 256, 0, stream>>>(h, outm16, basC16, ww16, w_b, a_w, blk);
  }
  k_fc12<<<dim3(X / 128, BB), 256, 0, stream>>>(h, w1fc16, fc1_b, fc2_w, fc2_b, out);
}

// Round 6
// 833.819 us; speedup vs baseline: 5.3636x; 1.4334x over previous
//
#include <hip/hip_runtime.h>
#include <hip/hip_bf16.h>

// SGNO1d: B=16, X=16384, Xp=16386, W=64, H=128, M=64, NB=4.
// MFMA bf16 pipeline. h kept in bf16 [b][c][XPAD] (numerically identical:
// every consumer rounded h to bf16 anyway). Only 64 modes survive ->
// rfft/irfft are dense DFT GEMMs; ghat = ag*(W2@DFT(gmid)+b2*XP*delta_m0).

#define BB 16
#define X 16384
#define XP 16386
#define XPAD 16512   // 129*128; rows 16B-aligned, pad zeros
#define W 64
#define H 128
#define M 64
#define NB 4
#define NC 3

typedef __hip_bfloat16 bf16;
typedef __attribute__((ext_vector_type(8))) short short8;
typedef __attribute__((ext_vector_type(4))) float floatx4;

__device__ __forceinline__ float gelu_f(float t){
  return 0.5f * t * (1.0f + erff(t * 0.70710678118654752440f));
}
__device__ __forceinline__ float softplus_f(float v){
  return (v > 20.f) ? v : log1pf(expf(v));
}
__device__ __forceinline__ short f2bs(float f){   // fp32 -> bf16 bits (RNE)
  union { float f; unsigned u; } v; v.f = f;
  unsigned r = (v.u + 0x7FFFu + ((v.u >> 16) & 1u)) >> 16;
  return (short)r;
}
__device__ __forceinline__ float bs2f(short s){
  union { unsigned u; float f; } v; v.u = ((unsigned)(unsigned short)s) << 16;
  return v.f;
}
#define MFMA(a,b,c) __builtin_amdgcn_mfma_f32_16x16x32_bf16((a),(b),(c),0,0,0)

// ---------------- bases (coalesced writes) ----------------
// basT16[mp][x] (2m:cos, 2m+1:+sin)  -> DFT B-operand rows along x
__global__ __launch_bounds__(256) void k_basisT(short* __restrict__ basT16){
  int idx = blockIdx.x * 256 + threadIdx.x;
  if (idx >= 128 * XPAD) return;
  int mp = idx / XPAD, x = idx - mp * XPAD;
  float v = 0.f;
  if (x < XP){
    int m = mp >> 1;
    int tt = (int)(((long long)x * (long long)m) % XP);
    float ang = 6.283185307179586477f * (float)tt / (float)XP;
    float s, c; sincosf(ang, &s, &c);
    v = (mp & 1) ? s : c;
  }
  basT16[idx] = f2bs(v);
}
// basC16[x][kp] (2m:cos, 2m+1:-sin)  -> iDFT A-operand rows along kp
__global__ __launch_bounds__(256) void k_basisC(short* __restrict__ basC16){
  int idx = blockIdx.x * 256 + threadIdx.x;
  if (idx >= XPAD * 128) return;
  int x = idx >> 7, kp = idx & 127;
  float v = 0.f;
  if (x < XP){
    int m = kp >> 1;
    int tt = (int)(((long long)x * (long long)m) % XP);
    float ang = 6.283185307179586477f * (float)tt / (float)XP;
    float s, c; sincosf(ang, &s, &c);
    v = (kp & 1) ? -s : c;
  }
  basC16[idx] = f2bs(v);
}

__global__ __launch_bounds__(256) void k_decay(const float* __restrict__ log_decay,
                                               float* __restrict__ expz,
                                               float* __restrict__ phi){
  int idx = blockIdx.x * 256 + threadIdx.x;
  if (idx >= NB * W * M) return;
  float z = -softplus_f(log_decay[idx]);
  expz[idx] = expf(z);
  float p;
  if (fabsf(z) < 1e-6f) p = 1.0f + 0.5f * z + z * z * (1.0f / 6.0f);
  else                  p = expm1f(z) / z;
  phi[idx] = p;
}

__global__ void k_filt(float* __restrict__ filt){
  int m = threadIdx.x;
  if (m < M){
    float g = (float)m / 63.0f;
    float r2 = g * g + 1e-12f;
    float r4 = r2 * r2;
    float r8 = r4 * r4;
    filt[m] = expf(-2.0f * r8);
  }
}

// bf16 weights: ww16=aw*w_w, w116=g_w1, w1fc16=fc1_w, w0fc16=fc0_w (K-padded 31->32)
__global__ __launch_bounds__(256) void k_prep(const float* __restrict__ w_w,
                                              const float* __restrict__ g_w1,
                                              const float* __restrict__ fc1_w,
                                              const float* __restrict__ fc0_w,
                                              const float* __restrict__ awr,
                                              short* __restrict__ ww16,
                                              short* __restrict__ w116,
                                              short* __restrict__ w1fc16,
                                              short* __restrict__ w0fc16){
  int idx = blockIdx.x * 256 + threadIdx.x;
  float aw = softplus_f(awr[0]);
  if (idx < 16384){ ww16[idx] = f2bs(aw * w_w[idx]); }
  else if (idx < 49152){ int i = idx - 16384; w116[i] = f2bs(g_w1[i]); }
  else if (idx < 57344){ int i = idx - 49152; w1fc16[i] = f2bs(fc1_w[i]); }
  else if (idx < 59392){
    int i = idx - 57344;                 // o*32+f
    int o = i >> 5, f = i & 31;
    w0fc16[i] = (f < 31) ? f2bs(fc0_w[o * 31 + f]) : (short)0;
  }
}

// ---------------- fc0 (MFMA): h16[c][x] = W0 @ [x,grid] + b0, pad zeros ----------------
__global__ __launch_bounds__(256) void k_fc0m(const float* __restrict__ xg,
                                              const float* __restrict__ gg,
                                              const short* __restrict__ w0fc16,
                                              const float* __restrict__ bg,
                                              short* __restrict__ h16){
  __shared__ short xs16[128][40];
  int b = blockIdx.y, bx = blockIdx.x, x0 = bx * 128, t = threadIdx.x;
  if (bx == 128){                       // pad block: h=0 for x in [X, XPAD)
    for (int i = t; i < 64 * 128; i += 256){
      int c = i >> 7, x = i & 127;
      h16[((size_t)b * 64 + c) * XPAD + x0 + x] = 0;
    }
    return;
  }
  for (int i = t; i < 3840; i += 256){
    int x = i / 30, f = i - x * 30;
    xs16[x][f] = f2bs(xg[((size_t)b * X + x0 + x) * 30 + f]);
  }
  if (t < 128){ xs16[t][30] = f2bs(gg[(size_t)b * X + x0 + t]); xs16[t][31] = 0; }
  __syncthreads();
  int w = t >> 6, l = t & 63, q = l >> 4, ln = l & 15;
  floatx4 acc[4][2];
  #pragma unroll
  for (int mt = 0; mt < 4; ++mt)
    #pragma unroll
    for (int nt = 0; nt < 2; ++nt) acc[mt][nt] = (floatx4){0.f,0.f,0.f,0.f};
  #pragma unroll
  for (int mt = 0; mt < 4; ++mt){
    short8 av = *(const short8*)&w0fc16[(mt * 16 + ln) * 32 + q * 8];
    #pragma unroll
    for (int nt = 0; nt < 2; ++nt){
      short8 bv = *(const short8*)&xs16[w * 32 + nt * 16 + ln][q * 8];
      acc[mt][nt] = MFMA(av, bv, acc[mt][nt]);
    }
  }
  #pragma unroll
  for (int mt = 0; mt < 4; ++mt)
    #pragma unroll
    for (int r = 0; r < 4; ++r){
      int o = mt * 16 + q * 4 + r;
      float bias = bg[o];
      #pragma unroll
      for (int nt = 0; nt < 2; ++nt){
        int x = x0 + w * 32 + nt * 16 + ln;
        h16[((size_t)b * 64 + o) * XPAD + x] = f2bs(acc[mt][nt][r] + bias);
      }
    }
}

// ---------------- gmid = gelu(W1 @ h + b1), bf16 [b][o2][XPAD] ----------------
__global__ __launch_bounds__(256) void k_gmid(const short* __restrict__ h16,
                                              const short* __restrict__ w116,
                                              const float* __restrict__ b1g,
                                              short* __restrict__ gmid16, int blk){
  __shared__ short hT[128][72];   // [x][c]
  int b = blockIdx.y, x0 = blockIdx.x * 128, t = threadIdx.x;
  int w = t >> 6, l = t & 63, q = l >> 4, ln = l & 15;
  for (int i = t; i < 8192; i += 256){
    int x = i & 127, c = i >> 7;
    hT[x][c] = h16[((size_t)b * 64 + c) * XPAD + x0 + x];
  }
  __syncthreads();
  floatx4 acc[2][8];
  #pragma unroll
  for (int mt = 0; mt < 2; ++mt)
    #pragma unroll
    for (int nt = 0; nt < 8; ++nt) acc[mt][nt] = (floatx4){0.f,0.f,0.f,0.f};
  #pragma unroll
  for (int ks = 0; ks < 2; ++ks){
    short8 a0 = *(const short8*)&w116[((size_t)blk * H + (w*2+0)*16 + ln) * 64 + ks*32 + q*8];
    short8 a1 = *(const short8*)&w116[((size_t)blk * H + (w*2+1)*16 + ln) * 64 + ks*32 + q*8];
    #pragma unroll
    for (int nt = 0; nt < 8; ++nt){
      short8 bv = *(const short8*)&hT[nt*16 + ln][ks*32 + q*8];
      acc[0][nt] = MFMA(a0, bv, acc[0][nt]);
      acc[1][nt] = MFMA(a1, bv, acc[1][nt]);
    }
  }
  #pragma unroll
  for (int mt = 0; mt < 2; ++mt){
    float bvv[4];
    #pragma unroll
    for (int r = 0; r < 4; ++r) bvv[r] = b1g[blk * H + (w*2+mt)*16 + q*4 + r];
    #pragma unroll
    for (int nt = 0; nt < 8; ++nt){
      int gx = x0 + nt*16 + ln;
      #pragma unroll
      for (int r = 0; r < 4; ++r){
        int o2 = (w*2+mt)*16 + q*4 + r;
        float vv = gelu_f(acc[mt][nt][r] + bvv[r]);
        gmid16[((size_t)b * H + o2) * XPAD + gx] = (gx < XP) ? f2bs(vv) : (short)0;
      }
    }
  }
}

// ---------------- DFT (64 modes), MFMA split-K, LDS-staged, fp32 atomics ----------------
__global__ __launch_bounds__(256) void k_dft(const short* __restrict__ h16,
                                             const short* __restrict__ gmid16,
                                             const short* __restrict__ basT16,
                                             float* __restrict__ vhat,
                                             float* __restrict__ gmidhat){
  __shared__ short srcT[64][136];
  __shared__ short basS[128][136];
  int b = blockIdx.y, z = blockIdx.z;
  int xb = blockIdx.x * 1024, t = threadIdx.x;
  int w = t >> 6, l = t & 63, q = l >> 4, ln = l & 15;
  const short* src = (z == 0) ? h16 + (size_t)b * 64 * XPAD
                              : gmid16 + ((size_t)b * H + (z - 1) * 64) * XPAD;
  floatx4 acc[8];
  #pragma unroll
  for (int i = 0; i < 8; ++i) acc[i] = (floatx4){0.f,0.f,0.f,0.f};
  for (int xc = xb; xc < xb + 1024 && xc < XPAD; xc += 128){
    __syncthreads();
    #pragma unroll
    for (int u = 0; u < 4; ++u){
      int idx = u * 256 + t;            // 0..1023
      int c = idx >> 4, col = (idx & 15) * 8;
      *(short8*)&srcT[c][col] = *(const short8*)&src[(size_t)c * XPAD + xc + col];
    }
    #pragma unroll
    for (int u = 0; u < 8; ++u){
      int idx = u * 256 + t;            // 0..2047
      int mp = idx >> 4, col = (idx & 15) * 8;
      *(short8*)&basS[mp][col] = *(const short8*)&basT16[(size_t)mp * XPAD + xc + col];
    }
    __syncthreads();
    #pragma unroll
    for (int ks = 0; ks < 4; ++ks){
      short8 av = *(const short8*)&srcT[w*16 + ln][ks*32 + q*8];
      #pragma unroll
      for (int nt = 0; nt < 8; ++nt){
        short8 bv = *(const short8*)&basS[nt*16 + ln][ks*32 + q*8];
        acc[nt] = MFMA(av, bv, acc[nt]);
      }
    }
  }
  #pragma unroll
  for (int nt = 0; nt < 8; ++nt)
    #pragma unroll
    for (int r = 0; r < 4; ++r){
      int mp = nt*16 + ln;
      int c  = w*16 + q*4 + r;
      float v = acc[nt][r];
      if (mp & 1) v = -v;                    // im = -sum(src*sin)
      if (z == 0) atomicAdd(&vhat[((size_t)b * W + c) * 128 + mp], v);
      else atomicAdd(&gmidhat[((size_t)b * H + (z-1)*64 + c) * 128 + mp], v);
    }
}

// ---------------- ghat = ag*(W2 @ gmidhat) + ag*b2*XP at m=0 ----------------
__global__ __launch_bounds__(256) void k_ghat(const float* __restrict__ gmidhat,
                                              const float* __restrict__ w2g,
                                              const float* __restrict__ b2g,
                                              const float* __restrict__ agr,
                                              float* __restrict__ ghat, int blk){
  __shared__ float w2s[64][133];
  int b = blockIdx.x, zg = blockIdx.y, t = threadIdx.x;
  float ag = softplus_f(agr[0]);
  for (int i = t; i < 8192; i += 256) w2s[i >> 7][i & 127] = w2g[(size_t)blk * 8192 + i];
  __syncthreads();
  int i = t & 63, ms = t >> 6;
  int mp0 = zg * 16 + ms * 4;
  for (int j = 0; j < 4; ++j){
    int mp = mp0 + j;
    float acc = 0.f;
    for (int c2 = 0; c2 < H; ++c2)
      acc = fmaf(w2s[i][c2], gmidhat[((size_t)b * H + c2) * 128 + mp], acc);
    if (mp == 0) acc += (float)XP * b2g[blk * W + i];
    ghat[((size_t)b * W + i) * 128 + mp] = ag * acc;
  }
}

// ---------------- out_m (fp32 VALU; bf16 output) ----------------
__global__ __launch_bounds__(256) void k_outm(const float* __restrict__ vhat,
                       const float* __restrict__ ghat,
                       const float* __restrict__ mix_re, const float* __restrict__ mix_im,
                       const float* __restrict__ expz, const float* __restrict__ phi,
                       const float* __restrict__ filt, short* __restrict__ outm16, int blk){
  int b = blockIdx.y, t = threadIdx.x;
  int m = t & 63, os = t >> 6;
  int o = blockIdx.x * 4 + os;
  const float* mre = mix_re + (size_t)blk * W * W * M + (size_t)o * M + m;
  const float* mim = mix_im + (size_t)blk * W * W * M + (size_t)o * M + m;
  float gr = 0.f, gi = 0.f;
  for (int i = 0; i < W; ++i){
    float gre = ghat[((size_t)b * W + i) * 128 + 2 * m];
    float gim = ghat[((size_t)b * W + i) * 128 + 2 * m + 1];
    float xr = mre[(size_t)i * W * M];
    float xi = mim[(size_t)i * W * M];
    gr = fmaf(gre, xr, gr); gr = fmaf(-gim, xi, gr);
    gi = fmaf(gre, xi, gi); gi = fmaf( gim, xr, gi);
  }
  int om = blk * W * M + o * M + m;
  float ez = expz[om], ph = phi[om], fl = filt[m];
  float vr = vhat[((size_t)b * W + o) * 128 + 2 * m];
  float vi = vhat[((size_t)b * W + o) * 128 + 2 * m + 1];
  float outr = fmaf(ez, vr, ph * fl * gr);
  float outi = fmaf(ez, vi, ph * fl * gi);
  float sc = ((m == 0) ? 1.0f : 2.0f) / (float)XP;   // fold irfft scaling
  outm16[((size_t)b * W + o) * 128 + 2 * m]     = f2bs(outr * sc);
  outm16[((size_t)b * W + o) * 128 + 2 * m + 1] = f2bs(outi * sc);
}

// ---------------- update: h = act(iDFT(out_m) + aw*(W h + b)), two-phase LDS ----------------
__global__ __launch_bounds__(256) void k_update(short* __restrict__ h16,
                                                const short* __restrict__ outm16,
                                                const short* __restrict__ basC16,
                                                const short* __restrict__ ww16,
                                                const float* __restrict__ wbg,
                                                const float* __restrict__ awr, int blk){
  __shared__ __align__(16) char smem[52224];
  short (*hT)[72]    = (short(*)[72])smem;             // phase1
  short (*wwS)[72]   = (short(*)[72])(smem + 18432);
  short (*basS)[136] = (short(*)[136])smem;            // phase2
  short (*omS)[136]  = (short(*)[136])(smem + 34816);
  int b = blockIdx.y, x0 = blockIdx.x * 128, t = threadIdx.x;
  int w = t >> 6, l = t & 63, q = l >> 4, ln = l & 15;
  float aw = softplus_f(awr[0]);
  for (int i = t; i < 8192; i += 256){
    int x = i & 127, c = i >> 7;
    hT[x][c] = h16[((size_t)b * 64 + c) * XPAD + x0 + x];
  }
  #pragma unroll
  for (int u = 0; u < 2; ++u){
    int idx = u * 256 + t;
    int o = idx >> 3, col = (idx & 7) * 8;
    *(short8*)&wwS[o][col] = *(const short8*)&ww16[((size_t)blk * W + o) * 64 + col];
  }
  __syncthreads();
  floatx4 acc[2][4];
  #pragma unroll
  for (int mt = 0; mt < 2; ++mt)
    #pragma unroll
    for (int nt = 0; nt < 4; ++nt) acc[mt][nt] = (floatx4){0.f,0.f,0.f,0.f};
  #pragma unroll
  for (int ks = 0; ks < 2; ++ks){                 // aw*W@h: K=64 (c)
    short8 a0 = *(const short8*)&hT[(w*2+0)*16 + ln][ks*32 + q*8];
    short8 a1 = *(const short8*)&hT[(w*2+1)*16 + ln][ks*32 + q*8];
    #pragma unroll
    for (int nt = 0; nt < 4; ++nt){
      short8 bv = *(const short8*)&wwS[nt*16 + ln][ks*32 + q*8];
      acc[0][nt] = MFMA(a0, bv, acc[0][nt]);
      acc[1][nt] = MFMA(a1, bv, acc[1][nt]);
    }
  }
  __syncthreads();
  #pragma unroll
  for (int u = 0; u < 8; ++u){
    int idx = u * 256 + t;
    int x = idx >> 4, col = (idx & 15) * 8;
    *(short8*)&basS[x][col] = *(const short8*)&basC16[(size_t)(x0 + x) * 128 + col];
  }
  #pragma unroll
  for (int u = 0; u < 4; ++u){
    int idx = u * 256 + t;
    int o = idx >> 4, col = (idx & 15) * 8;
    *(short8*)&omS[o][col] = *(const short8*)&outm16[((size_t)b * W + o) * 128 + col];
  }
  __syncthreads();
  #pragma unroll
  for (int ks = 0; ks < 4; ++ks){                 // etd: K=128 (kp)
    short8 a0 = *(const short8*)&basS[(w*2+0)*16 + ln][ks*32 + q*8];
    short8 a1 = *(const short8*)&basS[(w*2+1)*16 + ln][ks*32 + q*8];
    #pragma unroll
    for (int nt = 0; nt < 4; ++nt){
      short8 bv = *(const short8*)&omS[nt*16 + ln][ks*32 + q*8];
      acc[0][nt] = MFMA(a0, bv, acc[0][nt]);
      acc[1][nt] = MFMA(a1, bv, acc[1][nt]);
    }
  }
  #pragma unroll
  for (int mt = 0; mt < 2; ++mt)
    #pragma unroll
    for (int nt = 0; nt < 4; ++nt){
      int o = nt*16 + ln;
      int xbase = x0 + (w*2+mt)*16 + q*4;
      float wbv = aw * wbg[blk * W + o];
      short* hp = &h16[((size_t)b * 64 + o) * XPAD + xbase];
      if (xbase + 3 < XP){
        short4 sv;
        float u0 = acc[mt][nt][0] + wbv, u1 = acc[mt][nt][1] + wbv;
        float u2 = acc[mt][nt][2] + wbv, u3 = acc[mt][nt][3] + wbv;
        if (blk != NB - 1){ u0 = gelu_f(u0); u1 = gelu_f(u1); u2 = gelu_f(u2); u3 = gelu_f(u3); }
        sv.x = f2bs(u0); sv.y = f2bs(u1); sv.z = f2bs(u2); sv.w = f2bs(u3);
        *(short4*)hp = sv;
      } else {
        #pragma unroll
        for (int r = 0; r < 4; ++r){
          if (xbase + r < XP){
            float u = acc[mt][nt][r] + wbv;
            if (blk != NB - 1) u = gelu_f(u);
            hp[r] = f2bs(u);
          }
        }
      }
    }
}

// ---------------- fc12: MFMA fc1 + VALU fc2 -> out (fp32) ----------------
__global__ __launch_bounds__(256) void k_fc12(const short* __restrict__ h16,
                                              const short* __restrict__ w1fc16,
                                              const float* __restrict__ b1,
                                              const float* __restrict__ w2,
                                              const float* __restrict__ b2,
                                              float* __restrict__ out){
  __shared__ short hT[128][72];
  __shared__ short gT[128][136];
  __shared__ float w2s[NC][132];
  __shared__ float red[2][128][NC];
  int b = blockIdx.y, x0 = blockIdx.x * 128, t = threadIdx.x;
  int w = t >> 6, l = t & 63, q = l >> 4, ln = l & 15;
  for (int i = t; i < 8192; i += 256){
    int x = i & 127, c = i >> 7;
    hT[x][c] = h16[((size_t)b * 64 + c) * XPAD + x0 + x];
  }
  for (int i = t; i < NC * H; i += 256) w2s[i / H][i % H] = w2[i];
  __syncthreads();
  floatx4 acc[2][8];
  #pragma unroll
  for (int mt = 0; mt < 2; ++mt)
    #pragma unroll
    for (int nt = 0; nt < 8; ++nt) acc[mt][nt] = (floatx4){0.f,0.f,0.f,0.f};
  #pragma unroll
  for (int ks = 0; ks < 2; ++ks){
    short8 a0 = *(const short8*)&w1fc16[(size_t)((w*2+0)*16 + ln) * 64 + ks*32 + q*8];
    short8 a1 = *(const short8*)&w1fc16[(size_t)((w*2+1)*16 + ln) * 64 + ks*32 + q*8];
    #pragma unroll
    for (int nt = 0; nt < 8; ++nt){
      short8 bv = *(const short8*)&hT[nt*16 + ln][ks*32 + q*8];
      acc[0][nt] = MFMA(a0, bv, acc[0][nt]);
      acc[1][nt] = MFMA(a1, bv, acc[1][nt]);
    }
  }
  #pragma unroll
  for (int mt = 0; mt < 2; ++mt){
    float bvv[4];
    #pragma unroll
    for (int r = 0; r < 4; ++r) bvv[r] = b1[(w*2+mt)*16 + q*4 + r];
    #pragma unroll
    for (int nt = 0; nt < 8; ++nt){
      int x = nt*16 + ln;
      #pragma unroll
      for (int r = 0; r < 4; ++r)
        gT[x][(w*2+mt)*16 + q*4 + r] = f2bs(gelu_f(acc[mt][nt][r] + bvv[r]));
    }
  }
  __syncthreads();
  int x = t & 127, half = t >> 7;
  float a3[NC] = {0.f, 0.f, 0.f};
  for (int og = 0; og < 8; ++og){
    int o0 = half * 64 + og * 8;
    short8 gv = *(const short8*)&gT[x][o0];
    #pragma unroll
    for (int j = 0; j < 8; ++j){
      float gf = bs2f(gv[j]);
      #pragma unroll
      for (int n = 0; n < NC; ++n) a3[n] = fmaf(gf, w2s[n][o0 + j], a3[n]);
    }
  }
  #pragma unroll
  for (int n = 0; n < NC; ++n) red[half][x][n] = a3[n];
  __syncthreads();
  if (half == 0){
    #pragma unroll
    for (int n = 0; n < NC; ++n)
      out[((size_t)b * X + x0 + x) * NC + n] = red[0][x][n] + red[1][x][n] + b2[n];
  }
}

extern "C" void kernel_launch(void* const* d_in, const int* in_sizes, int n_in,
                              void* d_out, int out_size, void* d_ws, size_t ws_size,
                              hipStream_t stream){
  (void)in_sizes; (void)n_in; (void)out_size; (void)ws_size;
  const float* x        = (const float*)d_in[0];
  const float* grid     = (const float*)d_in[1];
  const float* fc0_w    = (const float*)d_in[2];
  const float* fc0_b    = (const float*)d_in[3];
  const float* fc1_w    = (const float*)d_in[4];
  const float* fc1_b    = (const float*)d_in[5];
  const float* fc2_w    = (const float*)d_in[6];
  const float* fc2_b    = (const float*)d_in[7];
  const float* g_w1     = (const float*)d_in[8];
  const float* g_b1     = (const float*)d_in[9];
  const float* g_w2     = (const float*)d_in[10];
  const float* g_b2     = (const float*)d_in[11];
  const float* w_w      = (const float*)d_in[12];
  const float* w_b      = (const float*)d_in[13];
  const float* log_dec  = (const float*)d_in[14];
  const float* mix_re   = (const float*)d_in[15];
  const float* mix_im   = (const float*)d_in[16];
  const float* a_w      = (const float*)d_in[17];
  const float* a_g      = (const float*)d_in[18];
  float* out = (float*)d_out;

  // workspace carve (~112 MB, 16B aligned)
  short* basC16 = (short*)d_ws;                         // XPAD*128
  short* basT16 = basC16 + (size_t)XPAD * 128;          // 128*XPAD
  short* h16    = basT16 + (size_t)128 * XPAD;          // BB*64*XPAD
  short* gmid16 = h16 + (size_t)BB * 64 * XPAD;         // BB*128*XPAD
  float* vhat   = (float*)(gmid16 + (size_t)BB * H * XPAD);
  float* gmidhat= vhat + (size_t)BB * W * 128;
  float* ghat   = gmidhat + (size_t)BB * H * 128;
  float* expz   = ghat + (size_t)BB * W * 128;
  float* phi    = expz + NB * W * M;
  float* filt   = phi + NB * W * M;
  short* outm16 = (short*)(filt + 64);
  short* ww16   = outm16 + (size_t)BB * W * 128;
  short* w116   = ww16 + NB * W * W;
  short* w1fc16 = w116 + NB * H * W;
  short* w0fc16 = w1fc16 + H * W;

  k_basisT<<<dim3((128 * XPAD + 255) / 256), 256, 0, stream>>>(basT16);
  k_basisC<<<dim3((XPAD * 128 + 255) / 256), 256, 0, stream>>>(basC16);
  k_decay<<<dim3((NB * W * M + 255) / 256), 256, 0, stream>>>(log_dec, expz, phi);
  k_filt<<<1, 64, 0, stream>>>(filt);
  k_prep<<<dim3(232), 256, 0, stream>>>(w_w, g_w1, fc1_w, fc0_w, a_w, ww16, w116, w1fc16, w0fc16);
  k_fc0m<<<dim3(129, BB), 256, 0, stream>>>(x, grid, w0fc16, fc0_b, h16);

  for (int blk = 0; blk < NB; ++blk){
    k_gmid<<<dim3(XPAD / 128, BB), 256, 0, stream>>>(h16, w116, g_b1, gmid16, blk);
    hipMemsetAsync(vhat, 0, (size_t)(BB * W * 128 + BB * H * 128) * sizeof(float), stream);
    k_dft<<<dim3(17, BB, 3), 256, 0, stream>>>(h16, gmid16, basT16, vhat, gmidhat);
    k_ghat<<<dim3(BB, 8), 256, 0, stream>>>(gmidhat, g_w2, g_b2, a_g, ghat, blk);
    k_outm<<<dim3(16, BB), 256, 0, stream>>>(vhat, ghat, mix_re, mix_im, expz, phi, filt, outm16, blk);
    k_update<<<dim3(XPAD / 128, BB), 256, 0, stream>>>(h16, outm16, basC16, ww16, w_b, a_w, blk);
  }
  k_fc12<<<dim3(X / 128, BB), 256, 0, stream>>>(h16, w1fc16, fc1_b, fc2_w, fc2_b, out);
}

// Round 7
// 774.883 us; speedup vs baseline: 5.7715x; 1.0761x over previous
//
#include <hip/hip_runtime.h>
#include <hip/hip_bf16.h>

// SGNO1d: B=16, X=16384, Xp=16386, W=64, H=128, M=64, NB=4.
// MFMA bf16 pipeline. h kept in bf16 [b][c][XPAD]. Only 64 modes survive ->
// rfft/irfft are dense DFT GEMMs; ghat = ag*(W2@DFT(gmid)+b2*XP*delta_m0).
// R7: gmid fused into k_dft (no gmid16 round-trip); fast tanh-gelu (~10 VALU
// vs ~50 for erff; max dev 4e-4 << bf16 step).

#define BB 16
#define X 16384
#define XP 16386
#define XPAD 16512   // 129*128; rows 16B-aligned, pad zeros
#define W 64
#define H 128
#define M 64
#define NB 4
#define NC 3

typedef __hip_bfloat16 bf16;
typedef __attribute__((ext_vector_type(8))) short short8;
typedef __attribute__((ext_vector_type(4))) float floatx4;

__device__ __forceinline__ float gelu_f(float x){
  // tanh-form gelu; tanh(y) = 1 - 2/(exp(2y)+1); handles +-inf overflow fine
  float x3 = x * x * x;
  float y2 = 1.5957691216f * x + 0.0713548162f * x3;   // 2*sqrt(2/pi)*(x+0.044715x^3)
  float e = __expf(y2);
  float th = 1.f - 2.f / (e + 1.f);
  return 0.5f * x * (1.f + th);
}
__device__ __forceinline__ float softplus_f(float v){
  return (v > 20.f) ? v : log1pf(expf(v));
}
__device__ __forceinline__ short f2bs(float f){   // fp32 -> bf16 bits (RNE)
  union { float f; unsigned u; } v; v.f = f;
  unsigned r = (v.u + 0x7FFFu + ((v.u >> 16) & 1u)) >> 16;
  return (short)r;
}
__device__ __forceinline__ float bs2f(short s){
  union { unsigned u; float f; } v; v.u = ((unsigned)(unsigned short)s) << 16;
  return v.f;
}
#define MFMA(a,b,c) __builtin_amdgcn_mfma_f32_16x16x32_bf16((a),(b),(c),0,0,0)

// ---------------- bases (coalesced writes) ----------------
__global__ __launch_bounds__(256) void k_basisT(short* __restrict__ basT16){
  int idx = blockIdx.x * 256 + threadIdx.x;
  if (idx >= 128 * XPAD) return;
  int mp = idx / XPAD, x = idx - mp * XPAD;
  float v = 0.f;
  if (x < XP){
    int m = mp >> 1;
    int tt = (int)(((long long)x * (long long)m) % XP);
    float ang = 6.283185307179586477f * (float)tt / (float)XP;
    float s, c; sincosf(ang, &s, &c);
    v = (mp & 1) ? s : c;
  }
  basT16[idx] = f2bs(v);
}
__global__ __launch_bounds__(256) void k_basisC(short* __restrict__ basC16){
  int idx = blockIdx.x * 256 + threadIdx.x;
  if (idx >= XPAD * 128) return;
  int x = idx >> 7, kp = idx & 127;
  float v = 0.f;
  if (x < XP){
    int m = kp >> 1;
    int tt = (int)(((long long)x * (long long)m) % XP);
    float ang = 6.283185307179586477f * (float)tt / (float)XP;
    float s, c; sincosf(ang, &s, &c);
    v = (kp & 1) ? -s : c;
  }
  basC16[idx] = f2bs(v);
}

__global__ __launch_bounds__(256) void k_decay(const float* __restrict__ log_decay,
                                               float* __restrict__ expz,
                                               float* __restrict__ phi){
  int idx = blockIdx.x * 256 + threadIdx.x;
  if (idx >= NB * W * M) return;
  float z = -softplus_f(log_decay[idx]);
  expz[idx] = expf(z);
  float p;
  if (fabsf(z) < 1e-6f) p = 1.0f + 0.5f * z + z * z * (1.0f / 6.0f);
  else                  p = expm1f(z) / z;
  phi[idx] = p;
}

__global__ void k_filt(float* __restrict__ filt){
  int m = threadIdx.x;
  if (m < M){
    float g = (float)m / 63.0f;
    float r2 = g * g + 1e-12f;
    float r4 = r2 * r2;
    float r8 = r4 * r4;
    filt[m] = expf(-2.0f * r8);
  }
}

// bf16 weights: ww16=aw*w_w, w116=g_w1, w1fc16=fc1_w, w0fc16=fc0_w (K 31->32)
__global__ __launch_bounds__(256) void k_prep(const float* __restrict__ w_w,
                                              const float* __restrict__ g_w1,
                                              const float* __restrict__ fc1_w,
                                              const float* __restrict__ fc0_w,
                                              const float* __restrict__ awr,
                                              short* __restrict__ ww16,
                                              short* __restrict__ w116,
                                              short* __restrict__ w1fc16,
                                              short* __restrict__ w0fc16){
  int idx = blockIdx.x * 256 + threadIdx.x;
  float aw = softplus_f(awr[0]);
  if (idx < 16384){ ww16[idx] = f2bs(aw * w_w[idx]); }
  else if (idx < 49152){ int i = idx - 16384; w116[i] = f2bs(g_w1[i]); }
  else if (idx < 57344){ int i = idx - 49152; w1fc16[i] = f2bs(fc1_w[i]); }
  else if (idx < 59392){
    int i = idx - 57344;
    int o = i >> 5, f = i & 31;
    w0fc16[i] = (f < 31) ? f2bs(fc0_w[o * 31 + f]) : (short)0;
  }
}

// ---------------- fc0 (MFMA): h16[c][x] = W0 @ [x,grid] + b0, pad zeros ----------------
__global__ __launch_bounds__(256) void k_fc0m(const float* __restrict__ xg,
                                              const float* __restrict__ gg,
                                              const short* __restrict__ w0fc16,
                                              const float* __restrict__ bg,
                                              short* __restrict__ h16){
  __shared__ short xs16[128][40];
  int b = blockIdx.y, bx = blockIdx.x, x0 = bx * 128, t = threadIdx.x;
  if (bx == 128){
    for (int i = t; i < 64 * 128; i += 256){
      int c = i >> 7, x = i & 127;
      h16[((size_t)b * 64 + c) * XPAD + x0 + x] = 0;
    }
    return;
  }
  for (int i = t; i < 3840; i += 256){
    int x = i / 30, f = i - x * 30;
    xs16[x][f] = f2bs(xg[((size_t)b * X + x0 + x) * 30 + f]);
  }
  if (t < 128){ xs16[t][30] = f2bs(gg[(size_t)b * X + x0 + t]); xs16[t][31] = 0; }
  __syncthreads();
  int w = t >> 6, l = t & 63, q = l >> 4, ln = l & 15;
  floatx4 acc[4][2];
  #pragma unroll
  for (int mt = 0; mt < 4; ++mt)
    #pragma unroll
    for (int nt = 0; nt < 2; ++nt) acc[mt][nt] = (floatx4){0.f,0.f,0.f,0.f};
  #pragma unroll
  for (int mt = 0; mt < 4; ++mt){
    short8 av = *(const short8*)&w0fc16[(mt * 16 + ln) * 32 + q * 8];
    #pragma unroll
    for (int nt = 0; nt < 2; ++nt){
      short8 bv = *(const short8*)&xs16[w * 32 + nt * 16 + ln][q * 8];
      acc[mt][nt] = MFMA(av, bv, acc[mt][nt]);
    }
  }
  #pragma unroll
  for (int mt = 0; mt < 4; ++mt)
    #pragma unroll
    for (int r = 0; r < 4; ++r){
      int o = mt * 16 + q * 4 + r;
      float bias = bg[o];
      #pragma unroll
      for (int nt = 0; nt < 2; ++nt){
        int x = x0 + w * 32 + nt * 16 + ln;
        h16[((size_t)b * 64 + o) * XPAD + x] = f2bs(acc[mt][nt][r] + bias);
      }
    }
}

// ---------------- DFT (64 modes) with fused gmid, MFMA split-K, fp32 atomics ----------------
// z=0: vhat += DFT(h). z=1/2: gmid=gelu(W1@h+b1) computed in-LDS, gmidhat += DFT(gmid).
__global__ __launch_bounds__(256) void k_dft(const short* __restrict__ h16,
                                             const short* __restrict__ w116,
                                             const float* __restrict__ b1g,
                                             const short* __restrict__ basT16,
                                             float* __restrict__ vhat,
                                             float* __restrict__ gmidhat, int blk){
  __shared__ __align__(16) char smem[52224];
  short (*srcT)[136] = (short(*)[136])smem;            // 64x136 (17.4 KB), persistent
  short (*hT)[72]    = (short(*)[72])(smem + 17408);   // 128x72 (18.4 KB), W1 phase
  short (*basS)[136] = (short(*)[136])(smem + 17408);  // 128x136 (34.8 KB), DFT phase
  int b = blockIdx.y, z = blockIdx.z, bx = blockIdx.x, t = threadIdx.x;
  int w = t >> 6, l = t & 63, q = l >> 4, ln = l & 15;
  const short* hbase = h16 + (size_t)b * 64 * XPAD;
  floatx4 acc[8];
  #pragma unroll
  for (int i = 0; i < 8; ++i) acc[i] = (floatx4){0.f,0.f,0.f,0.f};
  // hoisted W1 operands (z>=1)
  short8 aw1[2];
  float bias[4];
  if (z){
    #pragma unroll
    for (int ks = 0; ks < 2; ++ks)
      aw1[ks] = *(const short8*)&w116[((size_t)blk * H + (z-1)*64 + w*16 + ln) * 64 + ks*32 + q*8];
    #pragma unroll
    for (int r = 0; r < 4; ++r)
      bias[r] = b1g[blk * H + (z-1)*64 + w*16 + q*4 + r];
  }
  for (int ci = bx; ci < 129; ci += 17){
    int xc = ci * 128;
    __syncthreads();                           // prior-iter LDS reads done
    if (z == 0){
      #pragma unroll
      for (int u = 0; u < 4; ++u){
        int idx = u * 256 + t;                 // 0..1023
        int c = idx >> 4, col = (idx & 15) * 8;
        *(short8*)&srcT[c][col] = *(const short8*)&hbase[(size_t)c * XPAD + xc + col];
      }
    } else {
      for (int i = t; i < 8192; i += 256){     // hT[x][c] transpose
        int x = i & 127, c = i >> 7;
        hT[x][c] = hbase[(size_t)c * XPAD + xc + x];
      }
    }
    __syncthreads();
    if (z){
      floatx4 a2[8];
      #pragma unroll
      for (int i = 0; i < 8; ++i) a2[i] = (floatx4){0.f,0.f,0.f,0.f};
      #pragma unroll
      for (int ks = 0; ks < 2; ++ks){
        #pragma unroll
        for (int nt = 0; nt < 8; ++nt){
          short8 bv = *(const short8*)&hT[nt*16 + ln][ks*32 + q*8];
          a2[nt] = MFMA(aw1[ks], bv, a2[nt]);
        }
      }
      #pragma unroll
      for (int nt = 0; nt < 8; ++nt){
        int gx = xc + nt*16 + ln;
        #pragma unroll
        for (int r = 0; r < 4; ++r){
          int o = w*16 + q*4 + r;
          float vv = gelu_f(a2[nt][r] + bias[r]);
          srcT[o][nt*16 + ln] = (gx < XP) ? f2bs(vv) : (short)0;
        }
      }
    }
    __syncthreads();                           // hT reads done; srcT visible
    #pragma unroll
    for (int u = 0; u < 8; ++u){
      int idx = u * 256 + t;                   // 0..2047
      int mp = idx >> 4, col = (idx & 15) * 8;
      *(short8*)&basS[mp][col] = *(const short8*)&basT16[(size_t)mp * XPAD + xc + col];
    }
    __syncthreads();
    #pragma unroll
    for (int ks = 0; ks < 4; ++ks){
      short8 av = *(const short8*)&srcT[w*16 + ln][ks*32 + q*8];
      #pragma unroll
      for (int nt = 0; nt < 8; ++nt){
        short8 bv = *(const short8*)&basS[nt*16 + ln][ks*32 + q*8];
        acc[nt] = MFMA(av, bv, acc[nt]);
      }
    }
  }
  #pragma unroll
  for (int nt = 0; nt < 8; ++nt)
    #pragma unroll
    for (int r = 0; r < 4; ++r){
      int mp = nt*16 + ln;
      int c  = w*16 + q*4 + r;
      float v = acc[nt][r];
      if (mp & 1) v = -v;                      // im = -sum(src*sin)
      if (z == 0) atomicAdd(&vhat[((size_t)b * W + c) * 128 + mp], v);
      else atomicAdd(&gmidhat[((size_t)b * H + (z-1)*64 + c) * 128 + mp], v);
    }
}

// ---------------- ghat = ag*(W2 @ gmidhat) + ag*b2*XP at m=0 ----------------
__global__ __launch_bounds__(256) void k_ghat(const float* __restrict__ gmidhat,
                                              const float* __restrict__ w2g,
                                              const float* __restrict__ b2g,
                                              const float* __restrict__ agr,
                                              float* __restrict__ ghat, int blk){
  __shared__ float w2s[64][133];
  int b = blockIdx.x, zg = blockIdx.y, t = threadIdx.x;
  float ag = softplus_f(agr[0]);
  for (int i = t; i < 8192; i += 256) w2s[i >> 7][i & 127] = w2g[(size_t)blk * 8192 + i];
  __syncthreads();
  int i = t & 63, ms = t >> 6;
  int mp0 = zg * 16 + ms * 4;
  for (int j = 0; j < 4; ++j){
    int mp = mp0 + j;
    float acc = 0.f;
    for (int c2 = 0; c2 < H; ++c2)
      acc = fmaf(w2s[i][c2], gmidhat[((size_t)b * H + c2) * 128 + mp], acc);
    if (mp == 0) acc += (float)XP * b2g[blk * W + i];
    ghat[((size_t)b * W + i) * 128 + mp] = ag * acc;
  }
}

// ---------------- out_m (fp32 VALU; bf16 output) ----------------
__global__ __launch_bounds__(256) void k_outm(const float* __restrict__ vhat,
                       const float* __restrict__ ghat,
                       const float* __restrict__ mix_re, const float* __restrict__ mix_im,
                       const float* __restrict__ expz, const float* __restrict__ phi,
                       const float* __restrict__ filt, short* __restrict__ outm16, int blk){
  int b = blockIdx.y, t = threadIdx.x;
  int m = t & 63, os = t >> 6;
  int o = blockIdx.x * 4 + os;
  const float* mre = mix_re + (size_t)blk * W * W * M + (size_t)o * M + m;
  const float* mim = mix_im + (size_t)blk * W * W * M + (size_t)o * M + m;
  float gr = 0.f, gi = 0.f;
  for (int i = 0; i < W; ++i){
    float gre = ghat[((size_t)b * W + i) * 128 + 2 * m];
    float gim = ghat[((size_t)b * W + i) * 128 + 2 * m + 1];
    float xr = mre[(size_t)i * W * M];
    float xi = mim[(size_t)i * W * M];
    gr = fmaf(gre, xr, gr); gr = fmaf(-gim, xi, gr);
    gi = fmaf(gre, xi, gi); gi = fmaf( gim, xr, gi);
  }
  int om = blk * W * M + o * M + m;
  float ez = expz[om], ph = phi[om], fl = filt[m];
  float vr = vhat[((size_t)b * W + o) * 128 + 2 * m];
  float vi = vhat[((size_t)b * W + o) * 128 + 2 * m + 1];
  float outr = fmaf(ez, vr, ph * fl * gr);
  float outi = fmaf(ez, vi, ph * fl * gi);
  float sc = ((m == 0) ? 1.0f : 2.0f) / (float)XP;
  outm16[((size_t)b * W + o) * 128 + 2 * m]     = f2bs(outr * sc);
  outm16[((size_t)b * W + o) * 128 + 2 * m + 1] = f2bs(outi * sc);
}

// ---------------- update: h = act(iDFT(out_m) + aw*(W h + b)), two-phase LDS ----------------
__global__ __launch_bounds__(256) void k_update(short* __restrict__ h16,
                                                const short* __restrict__ outm16,
                                                const short* __restrict__ basC16,
                                                const short* __restrict__ ww16,
                                                const float* __restrict__ wbg,
                                                const float* __restrict__ awr, int blk){
  __shared__ __align__(16) char smem[52224];
  short (*hT)[72]    = (short(*)[72])smem;
  short (*wwS)[72]   = (short(*)[72])(smem + 18432);
  short (*basS)[136] = (short(*)[136])smem;
  short (*omS)[136]  = (short(*)[136])(smem + 34816);
  int b = blockIdx.y, x0 = blockIdx.x * 128, t = threadIdx.x;
  int w = t >> 6, l = t & 63, q = l >> 4, ln = l & 15;
  float aw = softplus_f(awr[0]);
  for (int i = t; i < 8192; i += 256){
    int x = i & 127, c = i >> 7;
    hT[x][c] = h16[((size_t)b * 64 + c) * XPAD + x0 + x];
  }
  #pragma unroll
  for (int u = 0; u < 2; ++u){
    int idx = u * 256 + t;
    int o = idx >> 3, col = (idx & 7) * 8;
    *(short8*)&wwS[o][col] = *(const short8*)&ww16[((size_t)blk * W + o) * 64 + col];
  }
  __syncthreads();
  floatx4 acc[2][4];
  #pragma unroll
  for (int mt = 0; mt < 2; ++mt)
    #pragma unroll
    for (int nt = 0; nt < 4; ++nt) acc[mt][nt] = (floatx4){0.f,0.f,0.f,0.f};
  #pragma unroll
  for (int ks = 0; ks < 2; ++ks){
    short8 a0 = *(const short8*)&hT[(w*2+0)*16 + ln][ks*32 + q*8];
    short8 a1 = *(const short8*)&hT[(w*2+1)*16 + ln][ks*32 + q*8];
    #pragma unroll
    for (int nt = 0; nt < 4; ++nt){
      short8 bv = *(const short8*)&wwS[nt*16 + ln][ks*32 + q*8];
      acc[0][nt] = MFMA(a0, bv, acc[0][nt]);
      acc[1][nt] = MFMA(a1, bv, acc[1][nt]);
    }
  }
  __syncthreads();
  #pragma unroll
  for (int u = 0; u < 8; ++u){
    int idx = u * 256 + t;
    int x = idx >> 4, col = (idx & 15) * 8;
    *(short8*)&basS[x][col] = *(const short8*)&basC16[(size_t)(x0 + x) * 128 + col];
  }
  #pragma unroll
  for (int u = 0; u < 4; ++u){
    int idx = u * 256 + t;
    int o = idx >> 4, col = (idx & 15) * 8;
    *(short8*)&omS[o][col] = *(const short8*)&outm16[((size_t)b * W + o) * 128 + col];
  }
  __syncthreads();
  #pragma unroll
  for (int ks = 0; ks < 4; ++ks){
    short8 a0 = *(const short8*)&basS[(w*2+0)*16 + ln][ks*32 + q*8];
    short8 a1 = *(const short8*)&basS[(w*2+1)*16 + ln][ks*32 + q*8];
    #pragma unroll
    for (int nt = 0; nt < 4; ++nt){
      short8 bv = *(const short8*)&omS[nt*16 + ln][ks*32 + q*8];
      acc[0][nt] = MFMA(a0, bv, acc[0][nt]);
      acc[1][nt] = MFMA(a1, bv, acc[1][nt]);
    }
  }
  #pragma unroll
  for (int mt = 0; mt < 2; ++mt)
    #pragma unroll
    for (int nt = 0; nt < 4; ++nt){
      int o = nt*16 + ln;
      int xbase = x0 + (w*2+mt)*16 + q*4;
      float wbv = aw * wbg[blk * W + o];
      short* hp = &h16[((size_t)b * 64 + o) * XPAD + xbase];
      if (xbase + 3 < XP){
        short4 sv;
        float u0 = acc[mt][nt][0] + wbv, u1 = acc[mt][nt][1] + wbv;
        float u2 = acc[mt][nt][2] + wbv, u3 = acc[mt][nt][3] + wbv;
        if (blk != NB - 1){ u0 = gelu_f(u0); u1 = gelu_f(u1); u2 = gelu_f(u2); u3 = gelu_f(u3); }
        sv.x = f2bs(u0); sv.y = f2bs(u1); sv.z = f2bs(u2); sv.w = f2bs(u3);
        *(short4*)hp = sv;
      } else {
        #pragma unroll
        for (int r = 0; r < 4; ++r){
          if (xbase + r < XP){
            float u = acc[mt][nt][r] + wbv;
            if (blk != NB - 1) u = gelu_f(u);
            hp[r] = f2bs(u);
          }
        }
      }
    }
}

// ---------------- fc12: MFMA fc1 + VALU fc2 -> out (fp32) ----------------
__global__ __launch_bounds__(256) void k_fc12(const short* __restrict__ h16,
                                              const short* __restrict__ w1fc16,
                                              const float* __restrict__ b1,
                                              const float* __restrict__ w2,
                                              const float* __restrict__ b2,
                                              float* __restrict__ out){
  __shared__ short hT[128][72];
  __shared__ short gT[128][136];
  __shared__ float w2s[NC][132];
  __shared__ float red[2][128][NC];
  int b = blockIdx.y, x0 = blockIdx.x * 128, t = threadIdx.x;
  int w = t >> 6, l = t & 63, q = l >> 4, ln = l & 15;
  for (int i = t; i < 8192; i += 256){
    int x = i & 127, c = i >> 7;
    hT[x][c] = h16[((size_t)b * 64 + c) * XPAD + x0 + x];
  }
  for (int i = t; i < NC * H; i += 256) w2s[i / H][i % H] = w2[i];
  __syncthreads();
  floatx4 acc[2][8];
  #pragma unroll
  for (int mt = 0; mt < 2; ++mt)
    #pragma unroll
    for (int nt = 0; nt < 8; ++nt) acc[mt][nt] = (floatx4){0.f,0.f,0.f,0.f};
  #pragma unroll
  for (int ks = 0; ks < 2; ++ks){
    short8 a0 = *(const short8*)&w1fc16[(size_t)((w*2+0)*16 + ln) * 64 + ks*32 + q*8];
    short8 a1 = *(const short8*)&w1fc16[(size_t)((w*2+1)*16 + ln) * 64 + ks*32 + q*8];
    #pragma unroll
    for (int nt = 0; nt < 8; ++nt){
      short8 bv = *(const short8*)&hT[nt*16 + ln][ks*32 + q*8];
      acc[0][nt] = MFMA(a0, bv, acc[0][nt]);
      acc[1][nt] = MFMA(a1, bv, acc[1][nt]);
    }
  }
  #pragma unroll
  for (int mt = 0; mt < 2; ++mt){
    float bvv[4];
    #pragma unroll
    for (int r = 0; r < 4; ++r) bvv[r] = b1[(w*2+mt)*16 + q*4 + r];
    #pragma unroll
    for (int nt = 0; nt < 8; ++nt){
      int x = nt*16 + ln;
      #pragma unroll
      for (int r = 0; r < 4; ++r)
        gT[x][(w*2+mt)*16 + q*4 + r] = f2bs(gelu_f(acc[mt][nt][r] + bvv[r]));
    }
  }
  __syncthreads();
  int x = t & 127, half = t >> 7;
  float a3[NC] = {0.f, 0.f, 0.f};
  for (int og = 0; og < 8; ++og){
    int o0 = half * 64 + og * 8;
    short8 gv = *(const short8*)&gT[x][o0];
    #pragma unroll
    for (int j = 0; j < 8; ++j){
      float gf = bs2f(gv[j]);
      #pragma unroll
      for (int n = 0; n < NC; ++n) a3[n] = fmaf(gf, w2s[n][o0 + j], a3[n]);
    }
  }
  #pragma unroll
  for (int n = 0; n < NC; ++n) red[half][x][n] = a3[n];
  __syncthreads();
  if (half == 0){
    #pragma unroll
    for (int n = 0; n < NC; ++n)
      out[((size_t)b * X + x0 + x) * NC + n] = red[0][x][n] + red[1][x][n] + b2[n];
  }
}

extern "C" void kernel_launch(void* const* d_in, const int* in_sizes, int n_in,
                              void* d_out, int out_size, void* d_ws, size_t ws_size,
                              hipStream_t stream){
  (void)in_sizes; (void)n_in; (void)out_size; (void)ws_size;
  const float* x        = (const float*)d_in[0];
  const float* grid     = (const float*)d_in[1];
  const float* fc0_w    = (const float*)d_in[2];
  const float* fc0_b    = (const float*)d_in[3];
  const float* fc1_w    = (const float*)d_in[4];
  const float* fc1_b    = (const float*)d_in[5];
  const float* fc2_w    = (const float*)d_in[6];
  const float* fc2_b    = (const float*)d_in[7];
  const float* g_w1     = (const float*)d_in[8];
  const float* g_b1     = (const float*)d_in[9];
  const float* g_w2     = (const float*)d_in[10];
  const float* g_b2     = (const float*)d_in[11];
  const float* w_w      = (const float*)d_in[12];
  const float* w_b      = (const float*)d_in[13];
  const float* log_dec  = (const float*)d_in[14];
  const float* mix_re   = (const float*)d_in[15];
  const float* mix_im   = (const float*)d_in[16];
  const float* a_w      = (const float*)d_in[17];
  const float* a_g      = (const float*)d_in[18];
  float* out = (float*)d_out;

  // workspace carve (~44 MB, 16B aligned)
  short* basC16 = (short*)d_ws;                         // XPAD*128
  short* basT16 = basC16 + (size_t)XPAD * 128;          // 128*XPAD
  short* h16    = basT16 + (size_t)128 * XPAD;          // BB*64*XPAD
  float* vhat   = (float*)(h16 + (size_t)BB * 64 * XPAD);
  float* gmidhat= vhat + (size_t)BB * W * 128;
  float* ghat   = gmidhat + (size_t)BB * H * 128;
  float* expz   = ghat + (size_t)BB * W * 128;
  float* phi    = expz + NB * W * M;
  float* filt   = phi + NB * W * M;
  short* outm16 = (short*)(filt + 64);
  short* ww16   = outm16 + (size_t)BB * W * 128;
  short* w116   = ww16 + NB * W * W;
  short* w1fc16 = w116 + NB * H * W;
  short* w0fc16 = w1fc16 + H * W;

  k_basisT<<<dim3((128 * XPAD + 255) / 256), 256, 0, stream>>>(basT16);
  k_basisC<<<dim3((XPAD * 128 + 255) / 256), 256, 0, stream>>>(basC16);
  k_decay<<<dim3((NB * W * M + 255) / 256), 256, 0, stream>>>(log_dec, expz, phi);
  k_filt<<<1, 64, 0, stream>>>(filt);
  k_prep<<<dim3(232), 256, 0, stream>>>(w_w, g_w1, fc1_w, fc0_w, a_w, ww16, w116, w1fc16, w0fc16);
  k_fc0m<<<dim3(129, BB), 256, 0, stream>>>(x, grid, w0fc16, fc0_b, h16);

  for (int blk = 0; blk < NB; ++blk){
    hipMemsetAsync(vhat, 0, (size_t)(BB * W * 128 + BB * H * 128) * sizeof(float), stream);
    k_dft<<<dim3(17, BB, 3), 256, 0, stream>>>(h16, w116, g_b1, basT16, vhat, gmidhat, blk);
    k_ghat<<<dim3(BB, 8), 256, 0, stream>>>(gmidhat, g_w2, g_b2, a_g, ghat, blk);
    k_outm<<<dim3(16, BB), 256, 0, stream>>>(vhat, ghat, mix_re, mix_im, expz, phi, filt, outm16, blk);
    k_update<<<dim3(XPAD / 128, BB), 256, 0, stream>>>(h16, outm16, basC16, ww16, w_b, a_w, blk);
  }
  k_fc12<<<dim3(X / 128, BB), 256, 0, stream>>>(h16, w1fc16, fc1_b, fc2_w, fc2_b, out);
}

// Round 8
// 681.923 us; speedup vs baseline: 6.5583x; 1.1363x over previous
//
#include <hip/hip_runtime.h>
#include <hip/hip_bf16.h>

// SGNO1d: B=16, X=16384, Xp=16386, W=64, H=128, M=64, NB=4.
// MFMA bf16 pipeline. h kept in TWO layouts: h16[b][c][XPAD] (DFT src rows)
// and hX[b][x][64] (transposed mirror for W1@h / W@h / fc1 staging) -- both
// written by producers; kills the scalar LDS transpose (8-way conflicts).
// Only 64 modes survive -> rfft/irfft are dense DFT GEMMs;
// ghat = ag*(W2@DFT(gmid)+b2*XP*delta_m0); gmid fused into k_dft.

#define BB 16
#define X 16384
#define XP 16386
#define XPAD 16512   // 129*128; rows 16B-aligned, pad zeros
#define W 64
#define H 128
#define M 64
#define NB 4
#define NC 3

typedef __hip_bfloat16 bf16;
typedef __attribute__((ext_vector_type(8))) short short8;
typedef __attribute__((ext_vector_type(4))) float floatx4;

__device__ __forceinline__ float gelu_f(float x){
  float x3 = x * x * x;
  float y2 = 1.5957691216f * x + 0.0713548162f * x3;
  float e = __expf(y2);
  float th = 1.f - 2.f / (e + 1.f);
  return 0.5f * x * (1.f + th);
}
__device__ __forceinline__ float softplus_f(float v){
  return (v > 20.f) ? v : log1pf(expf(v));
}
__device__ __forceinline__ short f2bs(float f){   // fp32 -> bf16 bits (RNE)
  union { float f; unsigned u; } v; v.f = f;
  unsigned r = (v.u + 0x7FFFu + ((v.u >> 16) & 1u)) >> 16;
  return (short)r;
}
__device__ __forceinline__ float bs2f(short s){
  union { unsigned u; float f; } v; v.u = ((unsigned)(unsigned short)s) << 16;
  return v.f;
}
#define MFMA(a,b,c) __builtin_amdgcn_mfma_f32_16x16x32_bf16((a),(b),(c),0,0,0)

// ---------------- bases (coalesced writes) ----------------
__global__ __launch_bounds__(256) void k_basisT(short* __restrict__ basT16){
  int idx = blockIdx.x * 256 + threadIdx.x;
  if (idx >= 128 * XPAD) return;
  int mp = idx / XPAD, x = idx - mp * XPAD;
  float v = 0.f;
  if (x < XP){
    int m = mp >> 1;
    int tt = (int)(((long long)x * (long long)m) % XP);
    float ang = 6.283185307179586477f * (float)tt / (float)XP;
    float s, c; sincosf(ang, &s, &c);
    v = (mp & 1) ? s : c;
  }
  basT16[idx] = f2bs(v);
}
__global__ __launch_bounds__(256) void k_basisC(short* __restrict__ basC16){
  int idx = blockIdx.x * 256 + threadIdx.x;
  if (idx >= XPAD * 128) return;
  int x = idx >> 7, kp = idx & 127;
  float v = 0.f;
  if (x < XP){
    int m = kp >> 1;
    int tt = (int)(((long long)x * (long long)m) % XP);
    float ang = 6.283185307179586477f * (float)tt / (float)XP;
    float s, c; sincosf(ang, &s, &c);
    v = (kp & 1) ? -s : c;
  }
  basC16[idx] = f2bs(v);
}

__global__ __launch_bounds__(256) void k_decay(const float* __restrict__ log_decay,
                                               float* __restrict__ expz,
                                               float* __restrict__ phi){
  int idx = blockIdx.x * 256 + threadIdx.x;
  if (idx >= NB * W * M) return;
  float z = -softplus_f(log_decay[idx]);
  expz[idx] = expf(z);
  float p;
  if (fabsf(z) < 1e-6f) p = 1.0f + 0.5f * z + z * z * (1.0f / 6.0f);
  else                  p = expm1f(z) / z;
  phi[idx] = p;
}

__global__ void k_filt(float* __restrict__ filt){
  int m = threadIdx.x;
  if (m < M){
    float g = (float)m / 63.0f;
    float r2 = g * g + 1e-12f;
    float r4 = r2 * r2;
    float r8 = r4 * r4;
    filt[m] = expf(-2.0f * r8);
  }
}

// bf16 weights: ww16=aw*w_w, w116=g_w1, w1fc16=fc1_w, w0fc16=fc0_w (K 31->32)
__global__ __launch_bounds__(256) void k_prep(const float* __restrict__ w_w,
                                              const float* __restrict__ g_w1,
                                              const float* __restrict__ fc1_w,
                                              const float* __restrict__ fc0_w,
                                              const float* __restrict__ awr,
                                              short* __restrict__ ww16,
                                              short* __restrict__ w116,
                                              short* __restrict__ w1fc16,
                                              short* __restrict__ w0fc16){
  int idx = blockIdx.x * 256 + threadIdx.x;
  float aw = softplus_f(awr[0]);
  if (idx < 16384){ ww16[idx] = f2bs(aw * w_w[idx]); }
  else if (idx < 49152){ int i = idx - 16384; w116[i] = f2bs(g_w1[i]); }
  else if (idx < 57344){ int i = idx - 49152; w1fc16[i] = f2bs(fc1_w[i]); }
  else if (idx < 59392){
    int i = idx - 57344;
    int o = i >> 5, f = i & 31;
    w0fc16[i] = (f < 31) ? f2bs(fc0_w[o * 31 + f]) : (short)0;
  }
}

// ---------------- fc0 (MFMA): h16 + hX, pad zeros ----------------
__global__ __launch_bounds__(256) void k_fc0m(const float* __restrict__ xg,
                                              const float* __restrict__ gg,
                                              const short* __restrict__ w0fc16,
                                              const float* __restrict__ bg,
                                              short* __restrict__ h16,
                                              short* __restrict__ hX){
  __shared__ short xs16[128][40];
  __shared__ short xp[128][72];
  int b = blockIdx.y, bx = blockIdx.x, x0 = bx * 128, t = threadIdx.x;
  if (bx == 128){                       // pad rows: zero h16 & hX
    for (int i = t; i < 64 * 128; i += 256){
      int c = i >> 7, x = i & 127;
      h16[((size_t)b * 64 + c) * XPAD + x0 + x] = 0;
    }
    short8 z8 = (short8){0,0,0,0,0,0,0,0};
    for (int u = 0; u < 4; ++u){
      int idx = u * 256 + t;
      int x = idx >> 3, col = (idx & 7) * 8;
      *(short8*)&hX[((size_t)b * XPAD + x0 + x) * 64 + col] = z8;
    }
    return;
  }
  for (int i = t; i < 3840; i += 256){
    int x = i / 30, f = i - x * 30;
    xs16[x][f] = f2bs(xg[((size_t)b * X + x0 + x) * 30 + f]);
  }
  if (t < 128){ xs16[t][30] = f2bs(gg[(size_t)b * X + x0 + t]); xs16[t][31] = 0; }
  __syncthreads();
  int w = t >> 6, l = t & 63, q = l >> 4, ln = l & 15;
  floatx4 acc[4][2];
  #pragma unroll
  for (int mt = 0; mt < 4; ++mt)
    #pragma unroll
    for (int nt = 0; nt < 2; ++nt) acc[mt][nt] = (floatx4){0.f,0.f,0.f,0.f};
  #pragma unroll
  for (int mt = 0; mt < 4; ++mt){
    short8 av = *(const short8*)&w0fc16[(mt * 16 + ln) * 32 + q * 8];
    #pragma unroll
    for (int nt = 0; nt < 2; ++nt){
      short8 bv = *(const short8*)&xs16[w * 32 + nt * 16 + ln][q * 8];
      acc[mt][nt] = MFMA(av, bv, acc[mt][nt]);
    }
  }
  #pragma unroll
  for (int mt = 0; mt < 4; ++mt)
    #pragma unroll
    for (int r = 0; r < 4; ++r){
      int o = mt * 16 + q * 4 + r;
      float bias = bg[o];
      #pragma unroll
      for (int nt = 0; nt < 2; ++nt){
        int xl = w * 32 + nt * 16 + ln;
        short s = f2bs(acc[mt][nt][r] + bias);
        h16[((size_t)b * 64 + o) * XPAD + x0 + xl] = s;
        xp[xl][o] = s;
      }
    }
  __syncthreads();
  #pragma unroll
  for (int u = 0; u < 4; ++u){
    int idx = u * 256 + t;
    int x = idx >> 3, col = (idx & 7) * 8;
    *(short8*)&hX[((size_t)b * XPAD + x0 + x) * 64 + col] = *(const short8*)&xp[x][col];
  }
}

// ---------------- DFT (64 modes) with fused gmid, MFMA split-K, fp32 atomics ----------------
// z=0: vhat += DFT(h). z=1/2: gmid=gelu(W1@h+b1) in-LDS, gmidhat += DFT(gmid).
__global__ __launch_bounds__(256) void k_dft(const short* __restrict__ h16,
                                             const short* __restrict__ hX,
                                             const short* __restrict__ w116,
                                             const float* __restrict__ b1g,
                                             const short* __restrict__ basT16,
                                             float* __restrict__ vhat,
                                             float* __restrict__ gmidhat, int blk){
  __shared__ __align__(16) char smem[52224];
  short (*srcT)[136] = (short(*)[136])smem;            // 64x136, persistent
  short (*hT)[72]    = (short(*)[72])(smem + 17408);   // 128x72, W1 phase
  short (*basS)[136] = (short(*)[136])(smem + 17408);  // 128x136, DFT phase
  int b = blockIdx.y, z = blockIdx.z, bx = blockIdx.x, t = threadIdx.x;
  int w = t >> 6, l = t & 63, q = l >> 4, ln = l & 15;
  const short* hbase = h16 + (size_t)b * 64 * XPAD;
  const short* hXb   = hX + (size_t)b * XPAD * 64;
  floatx4 acc[8];
  #pragma unroll
  for (int i = 0; i < 8; ++i) acc[i] = (floatx4){0.f,0.f,0.f,0.f};
  short8 aw1[2];
  float bias[4];
  if (z){
    #pragma unroll
    for (int ks = 0; ks < 2; ++ks)
      aw1[ks] = *(const short8*)&w116[((size_t)blk * H + (z-1)*64 + w*16 + ln) * 64 + ks*32 + q*8];
    #pragma unroll
    for (int r = 0; r < 4; ++r)
      bias[r] = b1g[blk * H + (z-1)*64 + w*16 + q*4 + r];
  }
  for (int ci = bx; ci < 129; ci += 17){
    int xc = ci * 128;
    __syncthreads();                           // prior-iter LDS reads done
    if (z == 0){
      #pragma unroll
      for (int u = 0; u < 4; ++u){
        int idx = u * 256 + t;
        int c = idx >> 4, col = (idx & 15) * 8;
        *(short8*)&srcT[c][col] = *(const short8*)&hbase[(size_t)c * XPAD + xc + col];
      }
    } else {
      #pragma unroll
      for (int u = 0; u < 4; ++u){             // hT[x][c] from hX rows (vector)
        int idx = u * 256 + t;
        int x = idx >> 3, col = (idx & 7) * 8;
        *(short8*)&hT[x][col] = *(const short8*)&hXb[(size_t)(xc + x) * 64 + col];
      }
    }
    __syncthreads();
    if (z){
      floatx4 a2[8];
      #pragma unroll
      for (int i = 0; i < 8; ++i) a2[i] = (floatx4){0.f,0.f,0.f,0.f};
      #pragma unroll
      for (int ks = 0; ks < 2; ++ks){
        #pragma unroll
        for (int nt = 0; nt < 8; ++nt){
          short8 bv = *(const short8*)&hT[nt*16 + ln][ks*32 + q*8];
          a2[nt] = MFMA(aw1[ks], bv, a2[nt]);
        }
      }
      #pragma unroll
      for (int nt = 0; nt < 8; ++nt){
        int gx = xc + nt*16 + ln;
        #pragma unroll
        for (int r = 0; r < 4; ++r){
          int o = w*16 + q*4 + r;
          float vv = gelu_f(a2[nt][r] + bias[r]);
          srcT[o][nt*16 + ln] = (gx < XP) ? f2bs(vv) : (short)0;
        }
      }
    }
    __syncthreads();                           // hT reads done; srcT visible
    #pragma unroll
    for (int u = 0; u < 8; ++u){
      int idx = u * 256 + t;
      int mp = idx >> 4, col = (idx & 15) * 8;
      *(short8*)&basS[mp][col] = *(const short8*)&basT16[(size_t)mp * XPAD + xc + col];
    }
    __syncthreads();
    #pragma unroll
    for (int ks = 0; ks < 4; ++ks){
      short8 av = *(const short8*)&srcT[w*16 + ln][ks*32 + q*8];
      #pragma unroll
      for (int nt = 0; nt < 8; ++nt){
        short8 bv = *(const short8*)&basS[nt*16 + ln][ks*32 + q*8];
        acc[nt] = MFMA(av, bv, acc[nt]);
      }
    }
  }
  #pragma unroll
  for (int nt = 0; nt < 8; ++nt)
    #pragma unroll
    for (int r = 0; r < 4; ++r){
      int mp = nt*16 + ln;
      int c  = w*16 + q*4 + r;
      float v = acc[nt][r];
      if (mp & 1) v = -v;                      // im = -sum(src*sin)
      if (z == 0) atomicAdd(&vhat[((size_t)b * W + c) * 128 + mp], v);
      else atomicAdd(&gmidhat[((size_t)b * H + (z-1)*64 + c) * 128 + mp], v);
    }
}

// ---------------- ghat = ag*(W2 @ gmidhat) + ag*b2*XP at m=0 ----------------
__global__ __launch_bounds__(256) void k_ghat(const float* __restrict__ gmidhat,
                                              const float* __restrict__ w2g,
                                              const float* __restrict__ b2g,
                                              const float* __restrict__ agr,
                                              float* __restrict__ ghat, int blk){
  __shared__ float w2s[64][133];
  int b = blockIdx.x, zg = blockIdx.y, t = threadIdx.x;
  float ag = softplus_f(agr[0]);
  for (int i = t; i < 8192; i += 256) w2s[i >> 7][i & 127] = w2g[(size_t)blk * 8192 + i];
  __syncthreads();
  int i = t & 63, ms = t >> 6;
  int mp0 = zg * 16 + ms * 4;
  for (int j = 0; j < 4; ++j){
    int mp = mp0 + j;
    float acc = 0.f;
    for (int c2 = 0; c2 < H; ++c2)
      acc = fmaf(w2s[i][c2], gmidhat[((size_t)b * H + c2) * 128 + mp], acc);
    if (mp == 0) acc += (float)XP * b2g[blk * W + i];
    ghat[((size_t)b * W + i) * 128 + mp] = ag * acc;
  }
}

// ---------------- out_m (fp32 VALU; bf16 output) ----------------
__global__ __launch_bounds__(256) void k_outm(const float* __restrict__ vhat,
                       const float* __restrict__ ghat,
                       const float* __restrict__ mix_re, const float* __restrict__ mix_im,
                       const float* __restrict__ expz, const float* __restrict__ phi,
                       const float* __restrict__ filt, short* __restrict__ outm16, int blk){
  int b = blockIdx.y, t = threadIdx.x;
  int m = t & 63, os = t >> 6;
  int o = blockIdx.x * 4 + os;
  const float* mre = mix_re + (size_t)blk * W * W * M + (size_t)o * M + m;
  const float* mim = mix_im + (size_t)blk * W * W * M + (size_t)o * M + m;
  float gr = 0.f, gi = 0.f;
  for (int i = 0; i < W; ++i){
    float gre = ghat[((size_t)b * W + i) * 128 + 2 * m];
    float gim = ghat[((size_t)b * W + i) * 128 + 2 * m + 1];
    float xr = mre[(size_t)i * W * M];
    float xi = mim[(size_t)i * W * M];
    gr = fmaf(gre, xr, gr); gr = fmaf(-gim, xi, gr);
    gi = fmaf(gre, xi, gi); gi = fmaf( gim, xr, gi);
  }
  int om = blk * W * M + o * M + m;
  float ez = expz[om], ph = phi[om], fl = filt[m];
  float vr = vhat[((size_t)b * W + o) * 128 + 2 * m];
  float vi = vhat[((size_t)b * W + o) * 128 + 2 * m + 1];
  float outr = fmaf(ez, vr, ph * fl * gr);
  float outi = fmaf(ez, vi, ph * fl * gi);
  float sc = ((m == 0) ? 1.0f : 2.0f) / (float)XP;
  outm16[((size_t)b * W + o) * 128 + 2 * m]     = f2bs(outr * sc);
  outm16[((size_t)b * W + o) * 128 + 2 * m + 1] = f2bs(outi * sc);
}

// ---------------- update: h = act(iDFT(out_m) + aw*(W h + b)), writes h16 + hX ----------------
__global__ __launch_bounds__(256) void k_update(short* __restrict__ h16,
                                                short* __restrict__ hX,
                                                const short* __restrict__ outm16,
                                                const short* __restrict__ basC16,
                                                const short* __restrict__ ww16,
                                                const float* __restrict__ wbg,
                                                const float* __restrict__ awr, int blk){
  __shared__ __align__(16) char smem[52224];
  short (*hT)[72]    = (short(*)[72])smem;
  short (*wwS)[72]   = (short(*)[72])(smem + 18432);
  short (*basS)[136] = (short(*)[136])smem;
  short (*omS)[136]  = (short(*)[136])(smem + 34816);
  short (*xp)[72]    = (short(*)[72])smem;             // epilogue retranspose
  int b = blockIdx.y, x0 = blockIdx.x * 128, t = threadIdx.x;
  int w = t >> 6, l = t & 63, q = l >> 4, ln = l & 15;
  float aw = softplus_f(awr[0]);
  const short* hXb = hX + (size_t)b * XPAD * 64;
  #pragma unroll
  for (int u = 0; u < 4; ++u){                 // hT from hX rows (vector)
    int idx = u * 256 + t;
    int x = idx >> 3, col = (idx & 7) * 8;
    *(short8*)&hT[x][col] = *(const short8*)&hXb[(size_t)(x0 + x) * 64 + col];
  }
  #pragma unroll
  for (int u = 0; u < 2; ++u){
    int idx = u * 256 + t;
    int o = idx >> 3, col = (idx & 7) * 8;
    *(short8*)&wwS[o][col] = *(const short8*)&ww16[((size_t)blk * W + o) * 64 + col];
  }
  __syncthreads();
  floatx4 acc[2][4];
  #pragma unroll
  for (int mt = 0; mt < 2; ++mt)
    #pragma unroll
    for (int nt = 0; nt < 4; ++nt) acc[mt][nt] = (floatx4){0.f,0.f,0.f,0.f};
  #pragma unroll
  for (int ks = 0; ks < 2; ++ks){
    short8 a0 = *(const short8*)&hT[(w*2+0)*16 + ln][ks*32 + q*8];
    short8 a1 = *(const short8*)&hT[(w*2+1)*16 + ln][ks*32 + q*8];
    #pragma unroll
    for (int nt = 0; nt < 4; ++nt){
      short8 bv = *(const short8*)&wwS[nt*16 + ln][ks*32 + q*8];
      acc[0][nt] = MFMA(a0, bv, acc[0][nt]);
      acc[1][nt] = MFMA(a1, bv, acc[1][nt]);
    }
  }
  __syncthreads();
  #pragma unroll
  for (int u = 0; u < 8; ++u){
    int idx = u * 256 + t;
    int x = idx >> 4, col = (idx & 15) * 8;
    *(short8*)&basS[x][col] = *(const short8*)&basC16[(size_t)(x0 + x) * 128 + col];
  }
  #pragma unroll
  for (int u = 0; u < 4; ++u){
    int idx = u * 256 + t;
    int o = idx >> 4, col = (idx & 15) * 8;
    *(short8*)&omS[o][col] = *(const short8*)&outm16[((size_t)b * W + o) * 128 + col];
  }
  __syncthreads();
  #pragma unroll
  for (int ks = 0; ks < 4; ++ks){
    short8 a0 = *(const short8*)&basS[(w*2+0)*16 + ln][ks*32 + q*8];
    short8 a1 = *(const short8*)&basS[(w*2+1)*16 + ln][ks*32 + q*8];
    #pragma unroll
    for (int nt = 0; nt < 4; ++nt){
      short8 bv = *(const short8*)&omS[nt*16 + ln][ks*32 + q*8];
      acc[0][nt] = MFMA(a0, bv, acc[0][nt]);
      acc[1][nt] = MFMA(a1, bv, acc[1][nt]);
    }
  }
  // epilogue: compute bf16 outputs, write h16 directly
  short sreg[2][4][4];
  #pragma unroll
  for (int mt = 0; mt < 2; ++mt)
    #pragma unroll
    for (int nt = 0; nt < 4; ++nt){
      int o = nt*16 + ln;
      int xbase = x0 + (w*2+mt)*16 + q*4;
      float wbv = aw * wbg[blk * W + o];
      short* hp = &h16[((size_t)b * 64 + o) * XPAD + xbase];
      #pragma unroll
      for (int r = 0; r < 4; ++r){
        float u = acc[mt][nt][r] + wbv;
        if (blk != NB - 1) u = gelu_f(u);
        sreg[mt][nt][r] = f2bs(u);
      }
      if (xbase + 3 < XP){
        *(short4*)hp = *(short4*)&sreg[mt][nt][0];
      } else {
        #pragma unroll
        for (int r = 0; r < 4; ++r)
          if (xbase + r < XP) hp[r] = sreg[mt][nt][r];
      }
    }
  __syncthreads();                             // basS/omS reads done
  #pragma unroll
  for (int mt = 0; mt < 2; ++mt)
    #pragma unroll
    for (int nt = 0; nt < 4; ++nt){
      int o = nt*16 + ln;
      int xl = (w*2+mt)*16 + q*4;
      #pragma unroll
      for (int r = 0; r < 4; ++r) xp[xl + r][o] = sreg[mt][nt][r];
    }
  __syncthreads();
  #pragma unroll
  for (int u = 0; u < 4; ++u){
    int idx = u * 256 + t;
    int x = idx >> 3, col = (idx & 7) * 8;
    if (x0 + x < XP)
      *(short8*)&hX[((size_t)b * XPAD + x0 + x) * 64 + col] = *(const short8*)&xp[x][col];
  }
}

// ---------------- fc12: MFMA fc1 + VALU fc2 -> out (fp32) ----------------
__global__ __launch_bounds__(256) void k_fc12(const short* __restrict__ hX,
                                              const short* __restrict__ w1fc16,
                                              const float* __restrict__ b1,
                                              const float* __restrict__ w2,
                                              const float* __restrict__ b2,
                                              float* __restrict__ out){
  __shared__ short hT[128][72];
  __shared__ short gT[128][136];
  __shared__ float w2s[NC][132];
  __shared__ float red[2][128][NC];
  int b = blockIdx.y, x0 = blockIdx.x * 128, t = threadIdx.x;
  int w = t >> 6, l = t & 63, q = l >> 4, ln = l & 15;
  const short* hXb = hX + (size_t)b * XPAD * 64;
  #pragma unroll
  for (int u = 0; u < 4; ++u){
    int idx = u * 256 + t;
    int x = idx >> 3, col = (idx & 7) * 8;
    *(short8*)&hT[x][col] = *(const short8*)&hXb[(size_t)(x0 + x) * 64 + col];
  }
  for (int i = t; i < NC * H; i += 256) w2s[i / H][i % H] = w2[i];
  __syncthreads();
  floatx4 acc[2][8];
  #pragma unroll
  for (int mt = 0; mt < 2; ++mt)
    #pragma unroll
    for (int nt = 0; nt < 8; ++nt) acc[mt][nt] = (floatx4){0.f,0.f,0.f,0.f};
  #pragma unroll
  for (int ks = 0; ks < 2; ++ks){
    short8 a0 = *(const short8*)&w1fc16[(size_t)((w*2+0)*16 + ln) * 64 + ks*32 + q*8];
    short8 a1 = *(const short8*)&w1fc16[(size_t)((w*2+1)*16 + ln) * 64 + ks*32 + q*8];
    #pragma unroll
    for (int nt = 0; nt < 8; ++nt){
      short8 bv = *(const short8*)&hT[nt*16 + ln][ks*32 + q*8];
      acc[0][nt] = MFMA(a0, bv, acc[0][nt]);
      acc[1][nt] = MFMA(a1, bv, acc[1][nt]);
    }
  }
  #pragma unroll
  for (int mt = 0; mt < 2; ++mt){
    float bvv[4];
    #pragma unroll
    for (int r = 0; r < 4; ++r) bvv[r] = b1[(w*2+mt)*16 + q*4 + r];
    #pragma unroll
    for (int nt = 0; nt < 8; ++nt){
      int x = nt*16 + ln;
      #pragma unroll
      for (int r = 0; r < 4; ++r)
        gT[x][(w*2+mt)*16 + q*4 + r] = f2bs(gelu_f(acc[mt][nt][r] + bvv[r]));
    }
  }
  __syncthreads();
  int x = t & 127, half = t >> 7;
  float a3[NC] = {0.f, 0.f, 0.f};
  for (int og = 0; og < 8; ++og){
    int o0 = half * 64 + og * 8;
    short8 gv = *(const short8*)&gT[x][o0];
    #pragma unroll
    for (int j = 0; j < 8; ++j){
      float gf = bs2f(gv[j]);
      #pragma unroll
      for (int n = 0; n < NC; ++n) a3[n] = fmaf(gf, w2s[n][o0 + j], a3[n]);
    }
  }
  #pragma unroll
  for (int n = 0; n < NC; ++n) red[half][x][n] = a3[n];
  __syncthreads();
  if (half == 0){
    #pragma unroll
    for (int n = 0; n < NC; ++n)
      out[((size_t)b * X + x0 + x) * NC + n] = red[0][x][n] + red[1][x][n] + b2[n];
  }
}

extern "C" void kernel_launch(void* const* d_in, const int* in_sizes, int n_in,
                              void* d_out, int out_size, void* d_ws, size_t ws_size,
                              hipStream_t stream){
  (void)in_sizes; (void)n_in; (void)out_size; (void)ws_size;
  const float* x        = (const float*)d_in[0];
  const float* grid     = (const float*)d_in[1];
  const float* fc0_w    = (const float*)d_in[2];
  const float* fc0_b    = (const float*)d_in[3];
  const float* fc1_w    = (const float*)d_in[4];
  const float* fc1_b    = (const float*)d_in[5];
  const float* fc2_w    = (const float*)d_in[6];
  const float* fc2_b    = (const float*)d_in[7];
  const float* g_w1     = (const float*)d_in[8];
  const float* g_b1     = (const float*)d_in[9];
  const float* g_w2     = (const float*)d_in[10];
  const float* g_b2     = (const float*)d_in[11];
  const float* w_w      = (const float*)d_in[12];
  const float* w_b      = (const float*)d_in[13];
  const float* log_dec  = (const float*)d_in[14];
  const float* mix_re   = (const float*)d_in[15];
  const float* mix_im   = (const float*)d_in[16];
  const float* a_w      = (const float*)d_in[17];
  const float* a_g      = (const float*)d_in[18];
  float* out = (float*)d_out;

  // workspace carve (~78 MB, 16B aligned)
  short* basC16 = (short*)d_ws;                         // XPAD*128
  short* basT16 = basC16 + (size_t)XPAD * 128;          // 128*XPAD
  short* h16    = basT16 + (size_t)128 * XPAD;          // BB*64*XPAD
  short* hX     = h16 + (size_t)BB * 64 * XPAD;         // BB*XPAD*64
  float* vhat   = (float*)(hX + (size_t)BB * XPAD * 64);
  float* gmidhat= vhat + (size_t)BB * W * 128;
  float* ghat   = gmidhat + (size_t)BB * H * 128;
  float* expz   = ghat + (size_t)BB * W * 128;
  float* phi    = expz + NB * W * M;
  float* filt   = phi + NB * W * M;
  short* outm16 = (short*)(filt + 64);
  short* ww16   = outm16 + (size_t)BB * W * 128;
  short* w116   = ww16 + NB * W * W;
  short* w1fc16 = w116 + NB * H * W;
  short* w0fc16 = w1fc16 + H * W;

  k_basisT<<<dim3((128 * XPAD + 255) / 256), 256, 0, stream>>>(basT16);
  k_basisC<<<dim3((XPAD * 128 + 255) / 256), 256, 0, stream>>>(basC16);
  k_decay<<<dim3((NB * W * M + 255) / 256), 256, 0, stream>>>(log_dec, expz, phi);
  k_filt<<<1, 64, 0, stream>>>(filt);
  k_prep<<<dim3(232), 256, 0, stream>>>(w_w, g_w1, fc1_w, fc0_w, a_w, ww16, w116, w1fc16, w0fc16);
  k_fc0m<<<dim3(129, BB), 256, 0, stream>>>(x, grid, w0fc16, fc0_b, h16, hX);

  for (int blk = 0; blk < NB; ++blk){
    hipMemsetAsync(vhat, 0, (size_t)(BB * W * 128 + BB * H * 128) * sizeof(float), stream);
    k_dft<<<dim3(17, BB, 3), 256, 0, stream>>>(h16, hX, w116, g_b1, basT16, vhat, gmidhat, blk);
    k_ghat<<<dim3(BB, 8), 256, 0, stream>>>(gmidhat, g_w2, g_b2, a_g, ghat, blk);
    k_outm<<<dim3(16, BB), 256, 0, stream>>>(vhat, ghat, mix_re, mix_im, expz, phi, filt, outm16, blk);
    k_update<<<dim3(XPAD / 128, BB), 256, 0, stream>>>(h16, hX, outm16, basC16, ww16, w_b, a_w, blk);
  }
  k_fc12<<<dim3(X / 128, BB), 256, 0, stream>>>(hX, w1fc16, fc1_b, fc2_w, fc2_b, out);
}